// Round 2
// baseline (941.559 us; speedup 1.0000x reference)
//
#include <hip/hip_runtime.h>
#include <hip/hip_bf16.h>
#include <math.h>

// ---------------------------------------------------------------------------
// LorentzAssignment on MI355X, fp32 end-to-end.
// Pipeline:
//   1. ass = softmax(logmap0(x) @ Wa^T)          [gemm128_kernel<0,true>]
//   2. q   = lorentz_linear(x, Wq, ls_q)         [gemm128_kernel<1,false>]
//   3. k   = lorentz_linear(x, Wk, ls_k)         [gemm128_kernel<1,false>]
//   4. score[e] = -acosh(clip(<q[src],k[dst]>_L))   + per-src edge counts
//   5. CSR build: scan(counts) + atomic fill
//   6. per-node: segment max/sum over scores, weighted sum of ass[dst] rows
//   7. gumbel-softmax with bit-exact JAX threefry2x32 (partitionable path)
// ---------------------------------------------------------------------------

#define D128 128

__device__ __forceinline__ void threefry2x32(unsigned x0, unsigned x1,
                                             unsigned& o0, unsigned& o1) {
  const unsigned k0 = 0u, k1 = 42u;
  const unsigned k2 = 0x1BD11BDAu ^ k0 ^ k1;
  x0 += k0; x1 += k1;
#define TF_ROT(r) { x0 += x1; x1 = (x1 << (r)) | (x1 >> (32 - (r))); x1 ^= x0; }
  TF_ROT(13) TF_ROT(15) TF_ROT(26) TF_ROT(6)
  x0 += k1; x1 += k2 + 1u;
  TF_ROT(17) TF_ROT(29) TF_ROT(16) TF_ROT(24)
  x0 += k2; x1 += k0 + 2u;
  TF_ROT(13) TF_ROT(15) TF_ROT(26) TF_ROT(6)
  x0 += k0; x1 += k1 + 3u;
  TF_ROT(17) TF_ROT(29) TF_ROT(16) TF_ROT(24)
  x0 += k1; x1 += k2 + 4u;
  TF_ROT(13) TF_ROT(15) TF_ROT(26) TF_ROT(6)
  x0 += k2; x1 += k0 + 5u;
#undef TF_ROT
  o0 = x0; o1 = x1;
}

// out = X @ W^T (N x 128, K=128), with optional logmap0 on the staged X tile,
// then row-wise postprocess: POST=0 softmax, POST=1 lorentz_linear tail.
template <int POST, bool DO_LOGMAP>
__global__ __launch_bounds__(256) void gemm128_kernel(
    const float* __restrict__ X, const float* __restrict__ W,
    const float* __restrict__ ls, float* __restrict__ out, int N) {
  __shared__ float xs[32][132];
  const int t = threadIdx.x;
  const int row0 = blockIdx.x * 32;

  // stage 32x128 tile (zero-fill OOB rows)
#pragma unroll
  for (int i = 0; i < 4; ++i) {
    int f = t + 256 * i;          // 1024 float4s in tile
    int r = f >> 5, c4 = f & 31;
    float4 v = make_float4(0.f, 0.f, 0.f, 0.f);
    if (row0 + r < N)
      v = *reinterpret_cast<const float4*>(X + (size_t)(row0 + r) * D128 + c4 * 4);
    *reinterpret_cast<float4*>(&xs[r][c4 * 4]) = v;
  }
  __syncthreads();

  if (DO_LOGMAP) {
    // logmap0 in-place on the tile: row -> [0, d * xs / ||xs||]
    int r = t >> 3, tr = t & 7;   // 8 threads per row, 16 cols each
    float ss = 0.f;
#pragma unroll
    for (int i = 0; i < 4; ++i) {
      float4 v = *reinterpret_cast<float4*>(&xs[r][tr * 16 + i * 4]);
      ss += v.x * v.x + v.y * v.y + v.z * v.z + v.w * v.w;
    }
    if (tr == 0) ss -= xs[r][0] * xs[r][0];   // exclude time component
#pragma unroll
    for (int msk = 1; msk < 8; msk <<= 1) ss += __shfl_xor(ss, msk);
    float x0v = xs[r][0];
    float dd = acoshf(fmaxf(x0v, 1.f + 1e-6f));
    float sc = dd / fmaxf(sqrtf(ss), 1e-8f);
#pragma unroll
    for (int i = 0; i < 4; ++i) {
      float4* p = reinterpret_cast<float4*>(&xs[r][tr * 16 + i * 4]);
      float4 v = *p;
      v.x *= sc; v.y *= sc; v.z *= sc; v.w *= sc;
      if (tr == 0 && i == 0) v.x = 0.f;
      *p = v;
    }
    __syncthreads();
  }

  const int cg = t & 15;          // column group: cols cg*8 .. cg*8+7
  const int rg = t >> 4;          // row group: rows 2rg, 2rg+1
  const int r0 = rg * 2, r1 = r0 + 1;
  float a0[8], a1[8];
#pragma unroll
  for (int j = 0; j < 8; ++j) { a0[j] = 0.f; a1[j] = 0.f; }
  const float* Wp = W + (size_t)cg * 8 * D128;

#pragma unroll 2
  for (int k = 0; k < D128; k += 4) {
    float4 xv0 = *reinterpret_cast<const float4*>(&xs[r0][k]);
    float4 xv1 = *reinterpret_cast<const float4*>(&xs[r1][k]);
#pragma unroll
    for (int j = 0; j < 8; ++j) {
      float4 w4 = *reinterpret_cast<const float4*>(Wp + j * D128 + k);
      a0[j] += xv0.x * w4.x + xv0.y * w4.y + xv0.z * w4.z + xv0.w * w4.w;
      a1[j] += xv1.x * w4.x + xv1.y * w4.y + xv1.z * w4.z + xv1.w * w4.w;
    }
  }

  const int lane = t & 63;
  const int gbase = lane & ~15;   // base lane of the 16-lane row team
  const int gr0 = row0 + r0, gr1 = row0 + r1;

  if (POST == 0) {
    // row softmax
    float m0 = -INFINITY, m1 = -INFINITY;
#pragma unroll
    for (int j = 0; j < 8; ++j) { m0 = fmaxf(m0, a0[j]); m1 = fmaxf(m1, a1[j]); }
#pragma unroll
    for (int msk = 1; msk < 16; msk <<= 1) {
      m0 = fmaxf(m0, __shfl_xor(m0, msk));
      m1 = fmaxf(m1, __shfl_xor(m1, msk));
    }
    float s0 = 0.f, s1 = 0.f;
#pragma unroll
    for (int j = 0; j < 8; ++j) {
      a0[j] = expf(a0[j] - m0); s0 += a0[j];
      a1[j] = expf(a1[j] - m1); s1 += a1[j];
    }
#pragma unroll
    for (int msk = 1; msk < 16; msk <<= 1) {
      s0 += __shfl_xor(s0, msk);
      s1 += __shfl_xor(s1, msk);
    }
    float i0 = 1.f / s0, i1 = 1.f / s1;
    if (gr0 < N) {
      float4 o = make_float4(a0[0] * i0, a0[1] * i0, a0[2] * i0, a0[3] * i0);
      *reinterpret_cast<float4*>(out + (size_t)gr0 * D128 + cg * 8) = o;
      o = make_float4(a0[4] * i0, a0[5] * i0, a0[6] * i0, a0[7] * i0);
      *reinterpret_cast<float4*>(out + (size_t)gr0 * D128 + cg * 8 + 4) = o;
    }
    if (gr1 < N) {
      float4 o = make_float4(a1[0] * i1, a1[1] * i1, a1[2] * i1, a1[3] * i1);
      *reinterpret_cast<float4*>(out + (size_t)gr1 * D128 + cg * 8) = o;
      o = make_float4(a1[4] * i1, a1[5] * i1, a1[6] * i1, a1[7] * i1);
      *reinterpret_cast<float4*>(out + (size_t)gr1 * D128 + cg * 8 + 4) = o;
    }
  } else {
    // lorentz_linear tail
    float scale = expf(ls[0]);
    float ss0 = 0.f, ss1 = 0.f;
#pragma unroll
    for (int j = 0; j < 8; ++j) {
      float v0 = a0[j], v1 = a1[j];
      if (cg == 0 && j == 0) { v0 = 0.f; v1 = 0.f; }   // narrow excludes col 0
      ss0 += v0 * v0; ss1 += v1 * v1;
    }
#pragma unroll
    for (int msk = 1; msk < 16; msk <<= 1) {
      ss0 += __shfl_xor(ss0, msk);
      ss1 += __shfl_xor(ss1, msk);
    }
    float y00 = __shfl(a0[0], gbase);
    float y10 = __shfl(a1[0], gbase);
    float t0 = scale / (1.f + expf(-y00)) + 1.1f;
    float t1 = scale / (1.f + expf(-y10)) + 1.1f;
    float q0 = sqrtf((t0 * t0 - 1.f) / fmaxf(ss0, 1e-8f));
    float q1 = sqrtf((t1 * t1 - 1.f) / fmaxf(ss1, 1e-8f));
    if (gr0 < N) {
      float o[8];
#pragma unroll
      for (int j = 0; j < 8; ++j) o[j] = a0[j] * q0;
      if (cg == 0) o[0] = t0;
      *reinterpret_cast<float4*>(out + (size_t)gr0 * D128 + cg * 8) =
          make_float4(o[0], o[1], o[2], o[3]);
      *reinterpret_cast<float4*>(out + (size_t)gr0 * D128 + cg * 8 + 4) =
          make_float4(o[4], o[5], o[6], o[7]);
    }
    if (gr1 < N) {
      float o[8];
#pragma unroll
      for (int j = 0; j < 8; ++j) o[j] = a1[j] * q1;
      if (cg == 0) o[0] = t1;
      *reinterpret_cast<float4*>(out + (size_t)gr1 * D128 + cg * 8) =
          make_float4(o[0], o[1], o[2], o[3]);
      *reinterpret_cast<float4*>(out + (size_t)gr1 * D128 + cg * 8 + 4) =
          make_float4(o[4], o[5], o[6], o[7]);
    }
  }
}

// score[e] = -acosh(clip(q0*k0 - sum_{c>=1} q_c*k_c, 1+1e-6)); counts[src]++
__global__ __launch_bounds__(256) void edge_score_kernel(
    const float* __restrict__ q, const float* __restrict__ k,
    const int* __restrict__ src, const int* __restrict__ dst,
    float* __restrict__ score, int* __restrict__ counts, int E) {
  int gid = blockIdx.x * 256 + threadIdx.x;
  int e = gid >> 4;
  int lg = threadIdx.x & 15;
  if (e >= E) return;
  int s = src[e], d = dst[e];
  const float4* qr = reinterpret_cast<const float4*>(q + (size_t)s * D128);
  const float4* kr = reinterpret_cast<const float4*>(k + (size_t)d * D128);
  float4 a0 = qr[lg * 2], a1 = qr[lg * 2 + 1];
  float4 b0 = kr[lg * 2], b1 = kr[lg * 2 + 1];
  float dot = a0.x * b0.x + a0.y * b0.y + a0.z * b0.z + a0.w * b0.w +
              a1.x * b1.x + a1.y * b1.y + a1.z * b1.z + a1.w * b1.w;
#pragma unroll
  for (int msk = 1; msk < 16; msk <<= 1) dot += __shfl_xor(dot, msk);
  if (lg == 0) {
    float inner = 2.f * a0.x * b0.x - dot;   // q0k0 - (dot - q0k0)
    score[e] = -acoshf(fmaxf(inner, 1.f + 1e-6f));
    atomicAdd(&counts[s], 1);
  }
}

// --- 3-kernel exclusive scan of counts -> start, cursor ---
__global__ __launch_bounds__(256) void scan1_kernel(const int* __restrict__ counts,
                                                    int* __restrict__ incl,
                                                    int* __restrict__ partials, int N) {
  int i = blockIdx.x * 256 + threadIdx.x;
  int c = (i < N) ? counts[i] : 0;
  int lane = threadIdx.x & 63, w = threadIdx.x >> 6;
  int v = c;
#pragma unroll
  for (int d = 1; d < 64; d <<= 1) {
    int tv = __shfl_up(v, d);
    if (lane >= d) v += tv;
  }
  __shared__ int wsum[4];
  if (lane == 63) wsum[w] = v;
  __syncthreads();
  int add = 0;
  for (int j = 0; j < w; ++j) add += wsum[j];
  v += add;
  if (i < N) incl[i] = v;
  if (threadIdx.x == 255) partials[blockIdx.x] = v;
}

__global__ __launch_bounds__(256) void scan2_kernel(int* __restrict__ partials, int nparts) {
  int t = threadIdx.x;
  int p = (t < nparts) ? partials[t] : 0;
  int lane = t & 63, w = t >> 6;
  int v = p;
#pragma unroll
  for (int d = 1; d < 64; d <<= 1) {
    int tv = __shfl_up(v, d);
    if (lane >= d) v += tv;
  }
  __shared__ int wsum[4];
  if (lane == 63) wsum[w] = v;
  __syncthreads();
  int add = 0;
  for (int j = 0; j < w; ++j) add += wsum[j];
  v += add;
  if (t < nparts) partials[t] = v - p;   // exclusive
}

__global__ __launch_bounds__(256) void scan3_kernel(const int* __restrict__ counts,
                                                    int* __restrict__ incl_to_start,
                                                    int* __restrict__ cursor,
                                                    const int* __restrict__ partials, int N) {
  int i = blockIdx.x * 256 + threadIdx.x;
  if (i < N) {
    int s = incl_to_start[i] - counts[i] + partials[blockIdx.x];
    incl_to_start[i] = s;
    cursor[i] = s;
  }
}

__global__ __launch_bounds__(256) void csr_fill_kernel(const int* __restrict__ src,
                                                       int* __restrict__ cursor,
                                                       int* __restrict__ csr, int E) {
  int e = blockIdx.x * 256 + threadIdx.x;
  if (e < E) {
    int pos = atomicAdd(&cursor[src[e]], 1);
    csr[pos] = e;
  }
}

// per-node: softmax over its edges' scores, weighted sum of ass[dst] rows
__global__ __launch_bounds__(256) void node_aggregate_kernel(
    const float* __restrict__ score, const float* __restrict__ ass,
    const int* __restrict__ csr, const int* __restrict__ start,
    const int* __restrict__ counts, const int* __restrict__ dst,
    float* __restrict__ out, int N) {
  int n = blockIdx.x * 4 + (threadIdx.x >> 6);
  if (n >= N) return;
  int lane = threadIdx.x & 63;
  int st = start[n], deg = counts[n];

  float m = -INFINITY;
  for (int i = lane; i < deg; i += 64) m = fmaxf(m, score[csr[st + i]]);
#pragma unroll
  for (int msk = 32; msk; msk >>= 1) m = fmaxf(m, __shfl_xor(m, msk));

  float ssum = 0.f;
  for (int i = lane; i < deg; i += 64) ssum += expf(score[csr[st + i]] - m);
#pragma unroll
  for (int msk = 32; msk; msk >>= 1) ssum += __shfl_xor(ssum, msk);
  float inv = 1.f / fmaxf(ssum, 1e-8f);

  float acc0 = 0.f, acc1 = 0.f;
  int c = lane * 2;
  for (int i = 0; i < deg; ++i) {
    int eid = csr[st + i];
    float w = expf(score[eid] - m) * inv;
    int d = dst[eid];
    float2 v = *reinterpret_cast<const float2*>(ass + (size_t)d * D128 + c);
    acc0 += w * v.x;
    acc1 += w * v.y;
  }
  *reinterpret_cast<float2*>(out + (size_t)n * D128 + c) = make_float2(acc0, acc1);
}

// in-place: out = softmax((log(out + 1e-6) + gumbel) / 0.2) per row
__global__ __launch_bounds__(256) void gumbel_softmax_kernel(float* __restrict__ out, int N) {
  int n = blockIdx.x * 4 + (threadIdx.x >> 6);
  if (n >= N) return;
  int lane = threadIdx.x & 63;
  float v[2];
#pragma unroll
  for (int jj = 0; jj < 2; ++jj) {
    int c = lane * 2 + jj;
    unsigned idx = (unsigned)(n * D128 + c);
    unsigned o0, o1;
    threefry2x32(0u, idx, o0, o1);   // partitionable path: hi=0, lo=i
    unsigned bits = o0 ^ o1;
    float f = __uint_as_float((bits >> 9) | 0x3f800000u) - 1.0f;
    float u = fmaxf(1e-10f, f * (1.0f - 1e-10f) + 1e-10f);
    float g = -logf(-logf(u));
    float a = out[(size_t)n * D128 + c];
    v[jj] = (logf(a + 1e-6f) + g) / 0.2f;
  }
  float m = fmaxf(v[0], v[1]);
#pragma unroll
  for (int msk = 32; msk; msk >>= 1) m = fmaxf(m, __shfl_xor(m, msk));
  float e0 = expf(v[0] - m), e1 = expf(v[1] - m);
  float s = e0 + e1;
#pragma unroll
  for (int msk = 32; msk; msk >>= 1) s += __shfl_xor(s, msk);
  float inv = 1.f / s;
  *reinterpret_cast<float2*>(out + (size_t)n * D128 + lane * 2) =
      make_float2(e0 * inv, e1 * inv);
}

extern "C" void kernel_launch(void* const* d_in, const int* in_sizes, int n_in,
                              void* d_out, int out_size, void* d_ws, size_t ws_size,
                              hipStream_t stream) {
  const float* x   = (const float*)d_in[0];
  const int*   src = (const int*)d_in[1];
  const int*   dst = (const int*)d_in[2];
  // d_in[3] = edge_value (unused by reference)
  const float* Wq  = (const float*)d_in[4];
  const float* Wk  = (const float*)d_in[5];
  const float* Wa  = (const float*)d_in[6];
  const float* lsq = (const float*)d_in[7];
  const float* lsk = (const float*)d_in[8];
  const int N = in_sizes[0] / D128;
  const int E = in_sizes[1];
  float* out = (float*)d_out;

  float* qbuf   = (float*)d_ws;
  float* kbuf   = qbuf + (size_t)N * D128;
  float* abuf   = kbuf + (size_t)N * D128;
  float* score  = abuf + (size_t)N * D128;
  int*   counts = (int*)(score + E);
  int*   startv = counts + N;
  int*   cursor = startv + N;
  int*   partials = cursor + N;
  int*   csr    = partials + 256;

  hipMemsetAsync(counts, 0, (size_t)N * sizeof(int), stream);

  const int gemm_blocks = (N + 31) / 32;
  gemm128_kernel<0, true ><<<gemm_blocks, 256, 0, stream>>>(x, Wa, nullptr, abuf, N);
  gemm128_kernel<1, false><<<gemm_blocks, 256, 0, stream>>>(x, Wq, lsq, qbuf, N);
  gemm128_kernel<1, false><<<gemm_blocks, 256, 0, stream>>>(x, Wk, lsk, kbuf, N);

  edge_score_kernel<<<(E + 15) / 16, 256, 0, stream>>>(qbuf, kbuf, src, dst, score, counts, E);

  const int nb = (N + 255) / 256;
  scan1_kernel<<<nb, 256, 0, stream>>>(counts, startv, partials, N);
  scan2_kernel<<<1, 256, 0, stream>>>(partials, nb);
  scan3_kernel<<<nb, 256, 0, stream>>>(counts, startv, cursor, partials, N);
  csr_fill_kernel<<<(E + 255) / 256, 256, 0, stream>>>(src, cursor, csr, E);

  node_aggregate_kernel<<<(N + 3) / 4, 256, 0, stream>>>(score, abuf, csr, startv,
                                                         counts, dst, out, N);
  gumbel_softmax_kernel<<<(N + 3) / 4, 256, 0, stream>>>(out, N);
}

// Round 5
// 478.764 us; speedup vs baseline: 1.9666x; 1.9666x over previous
//
#include <hip/hip_runtime.h>
#include <hip/hip_bf16.h>
#include <math.h>

// ---------------------------------------------------------------------------
// LorentzAssignment on MI355X, fp32 end-to-end.
//   1-3. three fused 50000x128 @ 128x128 GEMMs (ass/q/k) — W staged in LDS
//        (two 32KB K-halves), X tile in LDS, skewed layouts = conflict-free.
//   4. edge scores; 5. CSR build; 6. per-node softmax-aggregate; 7. gumbel.
// ---------------------------------------------------------------------------

#define D128 128

__device__ __forceinline__ void threefry2x32(unsigned x0, unsigned x1,
                                             unsigned& o0, unsigned& o1) {
  const unsigned k0 = 0u, k1 = 42u;
  const unsigned k2 = 0x1BD11BDAu ^ k0 ^ k1;
  x0 += k0; x1 += k1;
#define TF_ROT(r) { x0 += x1; x1 = (x1 << (r)) | (x1 >> (32 - (r))); x1 ^= x0; }
  TF_ROT(13) TF_ROT(15) TF_ROT(26) TF_ROT(6)
  x0 += k1; x1 += k2 + 1u;
  TF_ROT(17) TF_ROT(29) TF_ROT(16) TF_ROT(24)
  x0 += k2; x1 += k0 + 2u;
  TF_ROT(13) TF_ROT(15) TF_ROT(26) TF_ROT(6)
  x0 += k0; x1 += k1 + 3u;
  TF_ROT(17) TF_ROT(29) TF_ROT(16) TF_ROT(24)
  x0 += k1; x1 += k2 + 4u;
  TF_ROT(13) TF_ROT(15) TF_ROT(26) TF_ROT(6)
  x0 += k2; x1 += k0 + 5u;
#undef TF_ROT
  o0 = x0; o1 = x1;
}

// Skewed LDS addressing (float index of an aligned float4 chunk).
// X tile: 32 rows x 128 cols, chunk rotation within row, mask 31.
__device__ __forceinline__ int xaddr(int r, int k4) {
  return r * 128 + (((k4 + r) & 31) << 2);
}
// W half: 128 out-cols x 64 k, rotation driven by (c>>3) so the 16 col-groups
// spread across bank groups; mask 15.
__device__ __forceinline__ int waddr(int c, int k4) {
  return c * 64 + (((k4 + (c >> 3)) & 15) << 2);
}

// out = X @ W^T (N x 128, K=128), optional logmap0 on the staged X tile,
// then row-wise postprocess: POST=0 softmax, POST=1 lorentz_linear tail.
template <int POST, bool DO_LOGMAP>
__global__ __launch_bounds__(256) void gemm128_kernel(
    const float* __restrict__ X, const float* __restrict__ W,
    const float* __restrict__ ls, float* __restrict__ out, int N) {
  __shared__ float ws[128 * 64];   // 32 KB: one K-half of W, skewed
  __shared__ float xs[32 * 128];   // 16 KB: X tile, skewed

  const int t = threadIdx.x;
  const int row0 = blockIdx.x * 32;

  // ---- stage 32x128 X tile (zero-fill OOB rows), skewed ----
#pragma unroll
  for (int i = 0; i < 4; ++i) {
    int f = t + 256 * i;           // 1024 float4s
    int r = f >> 5, k4 = f & 31;
    float4 v = make_float4(0.f, 0.f, 0.f, 0.f);
    if (row0 + r < N)
      v = *reinterpret_cast<const float4*>(X + (size_t)(row0 + r) * D128 + k4 * 4);
    *reinterpret_cast<float4*>(&xs[xaddr(r, k4)]) = v;
  }
  __syncthreads();

  if (DO_LOGMAP) {
    // logmap0 in-place: row -> [0, d * narrow / ||narrow||]
    int r = t >> 3, tr = t & 7;    // 8 threads/row, 4 float4-chunks each
    float ss = 0.f;
    float4 ch[4];
#pragma unroll
    for (int i = 0; i < 4; ++i) {
      ch[i] = *reinterpret_cast<float4*>(&xs[xaddr(r, tr + 8 * i)]);
      ss += ch[i].x * ch[i].x + ch[i].y * ch[i].y + ch[i].z * ch[i].z + ch[i].w * ch[i].w;
    }
    if (tr == 0) ss -= ch[0].x * ch[0].x;   // exclude time component
#pragma unroll
    for (int msk = 1; msk < 8; msk <<= 1) ss += __shfl_xor(ss, msk);
    float x0v = __shfl(ch[0].x, (t & 63) & ~7);   // time elem from tr==0 lane
    float dd = acoshf(fmaxf(x0v, 1.f + 1e-6f));
    float sc = dd / fmaxf(sqrtf(ss), 1e-8f);
#pragma unroll
    for (int i = 0; i < 4; ++i) {
      float4 v = ch[i];
      v.x *= sc; v.y *= sc; v.z *= sc; v.w *= sc;
      if (tr == 0 && i == 0) v.x = 0.f;
      *reinterpret_cast<float4*>(&xs[xaddr(r, tr + 8 * i)]) = v;
    }
    __syncthreads();
  }

  const int cg = t & 15;           // col group: cols 8cg..8cg+7
  const int rg = t >> 4;           // row slot: rows rg and rg+16
  const int r0 = rg, r1 = rg + 16;
  float a0[8], a1[8];
#pragma unroll
  for (int j = 0; j < 8; ++j) { a0[j] = 0.f; a1[j] = 0.f; }

  // ---- two K-halves: stage 128x64 W half into LDS, then FMA sweep ----
  for (int h = 0; h < 2; ++h) {
    if (h) __syncthreads();        // protect ws reuse
#pragma unroll
    for (int i = 0; i < 8; ++i) {
      int f = t + 256 * i;         // 2048 float4s = 32 KB
      int c = f >> 4, k4 = f & 15;
      float4 v = *reinterpret_cast<const float4*>(W + (size_t)c * D128 + h * 64 + k4 * 4);
      *reinterpret_cast<float4*>(&ws[waddr(c, k4)]) = v;
    }
    __syncthreads();

#pragma unroll 4
    for (int kk = 0; kk < 16; ++kk) {
      int xk4 = h * 16 + kk;
      float4 xv0 = *reinterpret_cast<const float4*>(&xs[xaddr(r0, xk4)]);
      float4 xv1 = *reinterpret_cast<const float4*>(&xs[xaddr(r1, xk4)]);
#pragma unroll
      for (int j = 0; j < 8; ++j) {
        float4 w4 = *reinterpret_cast<const float4*>(&ws[waddr(cg * 8 + j, kk)]);
        a0[j] += xv0.x * w4.x + xv0.y * w4.y + xv0.z * w4.z + xv0.w * w4.w;
        a1[j] += xv1.x * w4.x + xv1.y * w4.y + xv1.z * w4.z + xv1.w * w4.w;
      }
    }
  }

  const int lane = t & 63;
  const int gbase = lane & ~15;    // base lane of the 16-lane row team
  const int gr0 = row0 + r0, gr1 = row0 + r1;

  if (POST == 0) {
    // row softmax
    float m0 = -INFINITY, m1 = -INFINITY;
#pragma unroll
    for (int j = 0; j < 8; ++j) { m0 = fmaxf(m0, a0[j]); m1 = fmaxf(m1, a1[j]); }
#pragma unroll
    for (int msk = 1; msk < 16; msk <<= 1) {
      m0 = fmaxf(m0, __shfl_xor(m0, msk));
      m1 = fmaxf(m1, __shfl_xor(m1, msk));
    }
    float s0 = 0.f, s1 = 0.f;
#pragma unroll
    for (int j = 0; j < 8; ++j) {
      a0[j] = expf(a0[j] - m0); s0 += a0[j];
      a1[j] = expf(a1[j] - m1); s1 += a1[j];
    }
#pragma unroll
    for (int msk = 1; msk < 16; msk <<= 1) {
      s0 += __shfl_xor(s0, msk);
      s1 += __shfl_xor(s1, msk);
    }
    float i0 = 1.f / s0, i1 = 1.f / s1;
    if (gr0 < N) {
      *reinterpret_cast<float4*>(out + (size_t)gr0 * D128 + cg * 8) =
          make_float4(a0[0] * i0, a0[1] * i0, a0[2] * i0, a0[3] * i0);
      *reinterpret_cast<float4*>(out + (size_t)gr0 * D128 + cg * 8 + 4) =
          make_float4(a0[4] * i0, a0[5] * i0, a0[6] * i0, a0[7] * i0);
    }
    if (gr1 < N) {
      *reinterpret_cast<float4*>(out + (size_t)gr1 * D128 + cg * 8) =
          make_float4(a1[0] * i1, a1[1] * i1, a1[2] * i1, a1[3] * i1);
      *reinterpret_cast<float4*>(out + (size_t)gr1 * D128 + cg * 8 + 4) =
          make_float4(a1[4] * i1, a1[5] * i1, a1[6] * i1, a1[7] * i1);
    }
  } else {
    // lorentz_linear tail
    float scale = expf(ls[0]);
    float ss0 = 0.f, ss1 = 0.f;
#pragma unroll
    for (int j = 0; j < 8; ++j) {
      float v0 = a0[j], v1 = a1[j];
      if (cg == 0 && j == 0) { v0 = 0.f; v1 = 0.f; }   // narrow excludes col 0
      ss0 += v0 * v0; ss1 += v1 * v1;
    }
#pragma unroll
    for (int msk = 1; msk < 16; msk <<= 1) {
      ss0 += __shfl_xor(ss0, msk);
      ss1 += __shfl_xor(ss1, msk);
    }
    float y00 = __shfl(a0[0], gbase);
    float y10 = __shfl(a1[0], gbase);
    float t0 = scale / (1.f + expf(-y00)) + 1.1f;
    float t1 = scale / (1.f + expf(-y10)) + 1.1f;
    float q0 = sqrtf((t0 * t0 - 1.f) / fmaxf(ss0, 1e-8f));
    float q1 = sqrtf((t1 * t1 - 1.f) / fmaxf(ss1, 1e-8f));
    if (gr0 < N) {
      float o[8];
#pragma unroll
      for (int j = 0; j < 8; ++j) o[j] = a0[j] * q0;
      if (cg == 0) o[0] = t0;
      *reinterpret_cast<float4*>(out + (size_t)gr0 * D128 + cg * 8) =
          make_float4(o[0], o[1], o[2], o[3]);
      *reinterpret_cast<float4*>(out + (size_t)gr0 * D128 + cg * 8 + 4) =
          make_float4(o[4], o[5], o[6], o[7]);
    }
    if (gr1 < N) {
      float o[8];
#pragma unroll
      for (int j = 0; j < 8; ++j) o[j] = a1[j] * q1;
      if (cg == 0) o[0] = t1;
      *reinterpret_cast<float4*>(out + (size_t)gr1 * D128 + cg * 8) =
          make_float4(o[0], o[1], o[2], o[3]);
      *reinterpret_cast<float4*>(out + (size_t)gr1 * D128 + cg * 8 + 4) =
          make_float4(o[4], o[5], o[6], o[7]);
    }
  }
}

// score[e] = -acosh(clip(q0*k0 - sum_{c>=1} q_c*k_c, 1+1e-6)); counts[src]++
__global__ __launch_bounds__(256) void edge_score_kernel(
    const float* __restrict__ q, const float* __restrict__ k,
    const int* __restrict__ src, const int* __restrict__ dst,
    float* __restrict__ score, int* __restrict__ counts, int E) {
  int gid = blockIdx.x * 256 + threadIdx.x;
  int e = gid >> 4;
  int lg = threadIdx.x & 15;
  if (e >= E) return;
  int s = src[e], d = dst[e];
  const float4* qr = reinterpret_cast<const float4*>(q + (size_t)s * D128);
  const float4* kr = reinterpret_cast<const float4*>(k + (size_t)d * D128);
  float4 a0 = qr[lg * 2], a1 = qr[lg * 2 + 1];
  float4 b0 = kr[lg * 2], b1 = kr[lg * 2 + 1];
  float dot = a0.x * b0.x + a0.y * b0.y + a0.z * b0.z + a0.w * b0.w +
              a1.x * b1.x + a1.y * b1.y + a1.z * b1.z + a1.w * b1.w;
#pragma unroll
  for (int msk = 1; msk < 16; msk <<= 1) dot += __shfl_xor(dot, msk);
  if (lg == 0) {
    float inner = 2.f * a0.x * b0.x - dot;   // q0k0 - (dot - q0k0)
    score[e] = -acoshf(fmaxf(inner, 1.f + 1e-6f));
    atomicAdd(&counts[s], 1);
  }
}

// --- 3-kernel exclusive scan of counts -> start, cursor ---
__global__ __launch_bounds__(256) void scan1_kernel(const int* __restrict__ counts,
                                                    int* __restrict__ incl,
                                                    int* __restrict__ partials, int N) {
  int i = blockIdx.x * 256 + threadIdx.x;
  int c = (i < N) ? counts[i] : 0;
  int lane = threadIdx.x & 63, w = threadIdx.x >> 6;
  int v = c;
#pragma unroll
  for (int d = 1; d < 64; d <<= 1) {
    int tv = __shfl_up(v, d);
    if (lane >= d) v += tv;
  }
  __shared__ int wsum[4];
  if (lane == 63) wsum[w] = v;
  __syncthreads();
  int add = 0;
  for (int j = 0; j < w; ++j) add += wsum[j];
  v += add;
  if (i < N) incl[i] = v;
  if (threadIdx.x == 255) partials[blockIdx.x] = v;
}

__global__ __launch_bounds__(256) void scan2_kernel(int* __restrict__ partials, int nparts) {
  int t = threadIdx.x;
  int p = (t < nparts) ? partials[t] : 0;
  int lane = t & 63, w = t >> 6;
  int v = p;
#pragma unroll
  for (int d = 1; d < 64; d <<= 1) {
    int tv = __shfl_up(v, d);
    if (lane >= d) v += tv;
  }
  __shared__ int wsum[4];
  if (lane == 63) wsum[w] = v;
  __syncthreads();
  int add = 0;
  for (int j = 0; j < w; ++j) add += wsum[j];
  v += add;
  if (t < nparts) partials[t] = v - p;   // exclusive
}

__global__ __launch_bounds__(256) void scan3_kernel(const int* __restrict__ counts,
                                                    int* __restrict__ incl_to_start,
                                                    int* __restrict__ cursor,
                                                    const int* __restrict__ partials, int N) {
  int i = blockIdx.x * 256 + threadIdx.x;
  if (i < N) {
    int s = incl_to_start[i] - counts[i] + partials[blockIdx.x];
    incl_to_start[i] = s;
    cursor[i] = s;
  }
}

__global__ __launch_bounds__(256) void csr_fill_kernel(const int* __restrict__ src,
                                                       int* __restrict__ cursor,
                                                       int* __restrict__ csr, int E) {
  int e = blockIdx.x * 256 + threadIdx.x;
  if (e < E) {
    int pos = atomicAdd(&cursor[src[e]], 1);
    csr[pos] = e;
  }
}

// per-node: softmax over its edges' scores, weighted sum of ass[dst] rows
__global__ __launch_bounds__(256) void node_aggregate_kernel(
    const float* __restrict__ score, const float* __restrict__ ass,
    const int* __restrict__ csr, const int* __restrict__ start,
    const int* __restrict__ counts, const int* __restrict__ dst,
    float* __restrict__ out, int N) {
  int n = blockIdx.x * 4 + (threadIdx.x >> 6);
  if (n >= N) return;
  int lane = threadIdx.x & 63;
  int st = start[n], deg = counts[n];

  float m = -INFINITY;
  for (int i = lane; i < deg; i += 64) m = fmaxf(m, score[csr[st + i]]);
#pragma unroll
  for (int msk = 32; msk; msk >>= 1) m = fmaxf(m, __shfl_xor(m, msk));

  float ssum = 0.f;
  for (int i = lane; i < deg; i += 64) ssum += expf(score[csr[st + i]] - m);
#pragma unroll
  for (int msk = 32; msk; msk >>= 1) ssum += __shfl_xor(ssum, msk);
  float inv = 1.f / fmaxf(ssum, 1e-8f);

  float acc0 = 0.f, acc1 = 0.f;
  int c = lane * 2;
  for (int i = 0; i < deg; ++i) {
    int eid = csr[st + i];
    float w = expf(score[eid] - m) * inv;
    int d = dst[eid];
    float2 v = *reinterpret_cast<const float2*>(ass + (size_t)d * D128 + c);
    acc0 += w * v.x;
    acc1 += w * v.y;
  }
  *reinterpret_cast<float2*>(out + (size_t)n * D128 + c) = make_float2(acc0, acc1);
}

// in-place: out = softmax((log(out + 1e-6) + gumbel) / 0.2) per row
__global__ __launch_bounds__(256) void gumbel_softmax_kernel(float* __restrict__ out, int N) {
  int n = blockIdx.x * 4 + (threadIdx.x >> 6);
  if (n >= N) return;
  int lane = threadIdx.x & 63;
  float v[2];
#pragma unroll
  for (int jj = 0; jj < 2; ++jj) {
    int c = lane * 2 + jj;
    unsigned idx = (unsigned)(n * D128 + c);
    unsigned o0, o1;
    threefry2x32(0u, idx, o0, o1);   // partitionable path: hi=0, lo=i
    unsigned bits = o0 ^ o1;
    float f = __uint_as_float((bits >> 9) | 0x3f800000u) - 1.0f;
    float u = fmaxf(1e-10f, f * (1.0f - 1e-10f) + 1e-10f);
    float g = -logf(-logf(u));
    float a = out[(size_t)n * D128 + c];
    v[jj] = (logf(a + 1e-6f) + g) / 0.2f;
  }
  float m = fmaxf(v[0], v[1]);
#pragma unroll
  for (int msk = 32; msk; msk >>= 1) m = fmaxf(m, __shfl_xor(m, msk));
  float e0 = expf(v[0] - m), e1 = expf(v[1] - m);
  float s = e0 + e1;
#pragma unroll
  for (int msk = 32; msk; msk >>= 1) s += __shfl_xor(s, msk);
  float inv = 1.f / s;
  *reinterpret_cast<float2*>(out + (size_t)n * D128 + lane * 2) =
      make_float2(e0 * inv, e1 * inv);
}

extern "C" void kernel_launch(void* const* d_in, const int* in_sizes, int n_in,
                              void* d_out, int out_size, void* d_ws, size_t ws_size,
                              hipStream_t stream) {
  const float* x   = (const float*)d_in[0];
  const int*   src = (const int*)d_in[1];
  const int*   dst = (const int*)d_in[2];
  // d_in[3] = edge_value (unused by reference)
  const float* Wq  = (const float*)d_in[4];
  const float* Wk  = (const float*)d_in[5];
  const float* Wa  = (const float*)d_in[6];
  const float* lsq = (const float*)d_in[7];
  const float* lsk = (const float*)d_in[8];
  const int N = in_sizes[0] / D128;
  const int E = in_sizes[1];
  float* out = (float*)d_out;

  float* qbuf   = (float*)d_ws;
  float* kbuf   = qbuf + (size_t)N * D128;
  float* abuf   = kbuf + (size_t)N * D128;
  float* score  = abuf + (size_t)N * D128;
  int*   counts = (int*)(score + E);
  int*   startv = counts + N;
  int*   cursor = startv + N;
  int*   partials = cursor + N;
  int*   csr    = partials + 256;

  hipMemsetAsync(counts, 0, (size_t)N * sizeof(int), stream);

  const int gemm_blocks = (N + 31) / 32;
  gemm128_kernel<0, true ><<<gemm_blocks, 256, 0, stream>>>(x, Wa, nullptr, abuf, N);
  gemm128_kernel<1, false><<<gemm_blocks, 256, 0, stream>>>(x, Wq, lsq, qbuf, N);
  gemm128_kernel<1, false><<<gemm_blocks, 256, 0, stream>>>(x, Wk, lsk, kbuf, N);

  edge_score_kernel<<<(E + 15) / 16, 256, 0, stream>>>(qbuf, kbuf, src, dst, score, counts, E);

  const int nb = (N + 255) / 256;
  scan1_kernel<<<nb, 256, 0, stream>>>(counts, startv, partials, N);
  scan2_kernel<<<1, 256, 0, stream>>>(partials, nb);
  scan3_kernel<<<nb, 256, 0, stream>>>(counts, startv, cursor, partials, N);
  csr_fill_kernel<<<(E + 255) / 256, 256, 0, stream>>>(src, cursor, csr, E);

  node_aggregate_kernel<<<(N + 3) / 4, 256, 0, stream>>>(score, abuf, csr, startv,
                                                         counts, dst, out, N);
  gumbel_softmax_kernel<<<(N + 3) / 4, 256, 0, stream>>>(out, N);
}

// Round 7
// 392.745 us; speedup vs baseline: 2.3974x; 1.2190x over previous
//
#include <hip/hip_runtime.h>
#include <hip/hip_bf16.h>
#include <hip/hip_fp16.h>
#include <math.h>

// ---------------------------------------------------------------------------
// LorentzAssignment on MI355X.
//   1-3. three fused 50000x128 @ 128x128 GEMMs (ass/q/k); W in LDS, skewed.
//        ass is written as fp16 (feeds only the edge-weighted aggregation).
//   4. edge scores + per-src counts; 5. CSR build scattering dst/score into
//      segment order; 6. fused per-node softmax-aggregate + gumbel-softmax.
// ---------------------------------------------------------------------------

#define D128 128

__device__ __forceinline__ void threefry2x32(unsigned x0, unsigned x1,
                                             unsigned& o0, unsigned& o1) {
  const unsigned k0 = 0u, k1 = 42u;
  const unsigned k2 = 0x1BD11BDAu ^ k0 ^ k1;
  x0 += k0; x1 += k1;
#define TF_ROT(r) { x0 += x1; x1 = (x1 << (r)) | (x1 >> (32 - (r))); x1 ^= x0; }
  TF_ROT(13) TF_ROT(15) TF_ROT(26) TF_ROT(6)
  x0 += k1; x1 += k2 + 1u;
  TF_ROT(17) TF_ROT(29) TF_ROT(16) TF_ROT(24)
  x0 += k2; x1 += k0 + 2u;
  TF_ROT(13) TF_ROT(15) TF_ROT(26) TF_ROT(6)
  x0 += k0; x1 += k1 + 3u;
  TF_ROT(17) TF_ROT(29) TF_ROT(16) TF_ROT(24)
  x0 += k1; x1 += k2 + 4u;
  TF_ROT(13) TF_ROT(15) TF_ROT(26) TF_ROT(6)
  x0 += k2; x1 += k0 + 5u;
#undef TF_ROT
  o0 = x0; o1 = x1;
}

// Skewed LDS addressing (float index of an aligned float4 chunk).
__device__ __forceinline__ int xaddr(int r, int k4) {
  return r * 128 + (((k4 + r) & 31) << 2);
}
__device__ __forceinline__ int waddr(int c, int k4) {
  return c * 64 + (((k4 + (c >> 3)) & 15) << 2);
}

// out = X @ W^T (N x 128, K=128), optional logmap0 on the staged X tile,
// then row-wise postprocess: POST=0 softmax (fp16 out), POST=1 lorentz tail.
template <int POST, bool DO_LOGMAP>
__global__ __launch_bounds__(256) void gemm128_kernel(
    const float* __restrict__ X, const float* __restrict__ W,
    const float* __restrict__ ls, float* __restrict__ out, int N) {
  __shared__ float ws[128 * 64];   // 32 KB: one K-half of W, skewed
  __shared__ float xs[32 * 128];   // 16 KB: X tile, skewed

  const int t = threadIdx.x;
  const int row0 = blockIdx.x * 32;

#pragma unroll
  for (int i = 0; i < 4; ++i) {
    int f = t + 256 * i;
    int r = f >> 5, k4 = f & 31;
    float4 v = make_float4(0.f, 0.f, 0.f, 0.f);
    if (row0 + r < N)
      v = *reinterpret_cast<const float4*>(X + (size_t)(row0 + r) * D128 + k4 * 4);
    *reinterpret_cast<float4*>(&xs[xaddr(r, k4)]) = v;
  }
  __syncthreads();

  if (DO_LOGMAP) {
    int r = t >> 3, tr = t & 7;
    float ss = 0.f;
    float4 ch[4];
#pragma unroll
    for (int i = 0; i < 4; ++i) {
      ch[i] = *reinterpret_cast<float4*>(&xs[xaddr(r, tr + 8 * i)]);
      ss += ch[i].x * ch[i].x + ch[i].y * ch[i].y + ch[i].z * ch[i].z + ch[i].w * ch[i].w;
    }
    if (tr == 0) ss -= ch[0].x * ch[0].x;
#pragma unroll
    for (int msk = 1; msk < 8; msk <<= 1) ss += __shfl_xor(ss, msk);
    float x0v = __shfl(ch[0].x, (t & 63) & ~7);
    float dd = acoshf(fmaxf(x0v, 1.f + 1e-6f));
    float sc = dd / fmaxf(sqrtf(ss), 1e-8f);
#pragma unroll
    for (int i = 0; i < 4; ++i) {
      float4 v = ch[i];
      v.x *= sc; v.y *= sc; v.z *= sc; v.w *= sc;
      if (tr == 0 && i == 0) v.x = 0.f;
      *reinterpret_cast<float4*>(&xs[xaddr(r, tr + 8 * i)]) = v;
    }
    __syncthreads();
  }

  const int cg = t & 15;
  const int rg = t >> 4;
  const int r0 = rg, r1 = rg + 16;
  float a0[8], a1[8];
#pragma unroll
  for (int j = 0; j < 8; ++j) { a0[j] = 0.f; a1[j] = 0.f; }

  for (int h = 0; h < 2; ++h) {
    if (h) __syncthreads();
#pragma unroll
    for (int i = 0; i < 8; ++i) {
      int f = t + 256 * i;
      int c = f >> 4, k4 = f & 15;
      float4 v = *reinterpret_cast<const float4*>(W + (size_t)c * D128 + h * 64 + k4 * 4);
      *reinterpret_cast<float4*>(&ws[waddr(c, k4)]) = v;
    }
    __syncthreads();

#pragma unroll 4
    for (int kk = 0; kk < 16; ++kk) {
      int xk4 = h * 16 + kk;
      float4 xv0 = *reinterpret_cast<const float4*>(&xs[xaddr(r0, xk4)]);
      float4 xv1 = *reinterpret_cast<const float4*>(&xs[xaddr(r1, xk4)]);
#pragma unroll
      for (int j = 0; j < 8; ++j) {
        float4 w4 = *reinterpret_cast<const float4*>(&ws[waddr(cg * 8 + j, kk)]);
        a0[j] += xv0.x * w4.x + xv0.y * w4.y + xv0.z * w4.z + xv0.w * w4.w;
        a1[j] += xv1.x * w4.x + xv1.y * w4.y + xv1.z * w4.z + xv1.w * w4.w;
      }
    }
  }

  const int lane = t & 63;
  const int gbase = lane & ~15;
  const int gr0 = row0 + r0, gr1 = row0 + r1;

  if (POST == 0) {
    // row softmax, fp16 output
    float m0 = -INFINITY, m1 = -INFINITY;
#pragma unroll
    for (int j = 0; j < 8; ++j) { m0 = fmaxf(m0, a0[j]); m1 = fmaxf(m1, a1[j]); }
#pragma unroll
    for (int msk = 1; msk < 16; msk <<= 1) {
      m0 = fmaxf(m0, __shfl_xor(m0, msk));
      m1 = fmaxf(m1, __shfl_xor(m1, msk));
    }
    float s0 = 0.f, s1 = 0.f;
#pragma unroll
    for (int j = 0; j < 8; ++j) {
      a0[j] = expf(a0[j] - m0); s0 += a0[j];
      a1[j] = expf(a1[j] - m1); s1 += a1[j];
    }
#pragma unroll
    for (int msk = 1; msk < 16; msk <<= 1) {
      s0 += __shfl_xor(s0, msk);
      s1 += __shfl_xor(s1, msk);
    }
    float i0 = 1.f / s0, i1 = 1.f / s1;
    __half* oh = reinterpret_cast<__half*>(out);
    if (gr0 < N) {
      union { __half2 h2[4]; uint4 u; } pk;
      pk.h2[0] = __floats2half2_rn(a0[0] * i0, a0[1] * i0);
      pk.h2[1] = __floats2half2_rn(a0[2] * i0, a0[3] * i0);
      pk.h2[2] = __floats2half2_rn(a0[4] * i0, a0[5] * i0);
      pk.h2[3] = __floats2half2_rn(a0[6] * i0, a0[7] * i0);
      *reinterpret_cast<uint4*>(oh + (size_t)gr0 * D128 + cg * 8) = pk.u;
    }
    if (gr1 < N) {
      union { __half2 h2[4]; uint4 u; } pk;
      pk.h2[0] = __floats2half2_rn(a1[0] * i1, a1[1] * i1);
      pk.h2[1] = __floats2half2_rn(a1[2] * i1, a1[3] * i1);
      pk.h2[2] = __floats2half2_rn(a1[4] * i1, a1[5] * i1);
      pk.h2[3] = __floats2half2_rn(a1[6] * i1, a1[7] * i1);
      *reinterpret_cast<uint4*>(oh + (size_t)gr1 * D128 + cg * 8) = pk.u;
    }
  } else {
    // lorentz_linear tail (fp32 out)
    float scale = expf(ls[0]);
    float ss0 = 0.f, ss1 = 0.f;
#pragma unroll
    for (int j = 0; j < 8; ++j) {
      float v0 = a0[j], v1 = a1[j];
      if (cg == 0 && j == 0) { v0 = 0.f; v1 = 0.f; }
      ss0 += v0 * v0; ss1 += v1 * v1;
    }
#pragma unroll
    for (int msk = 1; msk < 16; msk <<= 1) {
      ss0 += __shfl_xor(ss0, msk);
      ss1 += __shfl_xor(ss1, msk);
    }
    float y00 = __shfl(a0[0], gbase);
    float y10 = __shfl(a1[0], gbase);
    float t0 = scale / (1.f + expf(-y00)) + 1.1f;
    float t1 = scale / (1.f + expf(-y10)) + 1.1f;
    float q0 = sqrtf((t0 * t0 - 1.f) / fmaxf(ss0, 1e-8f));
    float q1 = sqrtf((t1 * t1 - 1.f) / fmaxf(ss1, 1e-8f));
    if (gr0 < N) {
      float o[8];
#pragma unroll
      for (int j = 0; j < 8; ++j) o[j] = a0[j] * q0;
      if (cg == 0) o[0] = t0;
      *reinterpret_cast<float4*>(out + (size_t)gr0 * D128 + cg * 8) =
          make_float4(o[0], o[1], o[2], o[3]);
      *reinterpret_cast<float4*>(out + (size_t)gr0 * D128 + cg * 8 + 4) =
          make_float4(o[4], o[5], o[6], o[7]);
    }
    if (gr1 < N) {
      float o[8];
#pragma unroll
      for (int j = 0; j < 8; ++j) o[j] = a1[j] * q1;
      if (cg == 0) o[0] = t1;
      *reinterpret_cast<float4*>(out + (size_t)gr1 * D128 + cg * 8) =
          make_float4(o[0], o[1], o[2], o[3]);
      *reinterpret_cast<float4*>(out + (size_t)gr1 * D128 + cg * 8 + 4) =
          make_float4(o[4], o[5], o[6], o[7]);
    }
  }
}

// score[e] = -acosh(clip(q0*k0 - sum_{c>=1} q_c*k_c, 1+1e-6)); counts[src]++
__global__ __launch_bounds__(256) void edge_score_kernel(
    const float* __restrict__ q, const float* __restrict__ k,
    const int* __restrict__ src, const int* __restrict__ dst,
    float* __restrict__ score, int* __restrict__ counts, int E) {
  int gid = blockIdx.x * 256 + threadIdx.x;
  int e = gid >> 4;
  int lg = threadIdx.x & 15;
  if (e >= E) return;
  int s = src[e], d = dst[e];
  const float4* qr = reinterpret_cast<const float4*>(q + (size_t)s * D128);
  const float4* kr = reinterpret_cast<const float4*>(k + (size_t)d * D128);
  float4 a0 = qr[lg * 2], a1 = qr[lg * 2 + 1];
  float4 b0 = kr[lg * 2], b1 = kr[lg * 2 + 1];
  float dot = a0.x * b0.x + a0.y * b0.y + a0.z * b0.z + a0.w * b0.w +
              a1.x * b1.x + a1.y * b1.y + a1.z * b1.z + a1.w * b1.w;
#pragma unroll
  for (int msk = 1; msk < 16; msk <<= 1) dot += __shfl_xor(dot, msk);
  if (lg == 0) {
    float inner = 2.f * a0.x * b0.x - dot;
    score[e] = -acoshf(fmaxf(inner, 1.f + 1e-6f));
    atomicAdd(&counts[s], 1);
  }
}

// --- 3-kernel exclusive scan of counts -> start, cursor ---
__global__ __launch_bounds__(256) void scan1_kernel(const int* __restrict__ counts,
                                                    int* __restrict__ incl,
                                                    int* __restrict__ partials, int N) {
  int i = blockIdx.x * 256 + threadIdx.x;
  int c = (i < N) ? counts[i] : 0;
  int lane = threadIdx.x & 63, w = threadIdx.x >> 6;
  int v = c;
#pragma unroll
  for (int d = 1; d < 64; d <<= 1) {
    int tv = __shfl_up(v, d);
    if (lane >= d) v += tv;
  }
  __shared__ int wsum[4];
  if (lane == 63) wsum[w] = v;
  __syncthreads();
  int add = 0;
  for (int j = 0; j < w; ++j) add += wsum[j];
  v += add;
  if (i < N) incl[i] = v;
  if (threadIdx.x == 255) partials[blockIdx.x] = v;
}

__global__ __launch_bounds__(256) void scan2_kernel(int* __restrict__ partials, int nparts) {
  int t = threadIdx.x;
  int p = (t < nparts) ? partials[t] : 0;
  int lane = t & 63, w = t >> 6;
  int v = p;
#pragma unroll
  for (int d = 1; d < 64; d <<= 1) {
    int tv = __shfl_up(v, d);
    if (lane >= d) v += tv;
  }
  __shared__ int wsum[4];
  if (lane == 63) wsum[w] = v;
  __syncthreads();
  int add = 0;
  for (int j = 0; j < w; ++j) add += wsum[j];
  v += add;
  if (t < nparts) partials[t] = v - p;
}

__global__ __launch_bounds__(256) void scan3_kernel(const int* __restrict__ counts,
                                                    int* __restrict__ incl_to_start,
                                                    int* __restrict__ cursor,
                                                    const int* __restrict__ partials, int N) {
  int i = blockIdx.x * 256 + threadIdx.x;
  if (i < N) {
    int s = incl_to_start[i] - counts[i] + partials[blockIdx.x];
    incl_to_start[i] = s;
    cursor[i] = s;
  }
}

// scatter dst & score into CSR (segment-sorted) order — no csr index array
__global__ __launch_bounds__(256) void csr_fill_kernel(
    const int* __restrict__ src, const int* __restrict__ dst,
    const float* __restrict__ score, int* __restrict__ cursor,
    int* __restrict__ dst_s, float* __restrict__ score_s, int E) {
  int e = blockIdx.x * 256 + threadIdx.x;
  if (e < E) {
    int pos = atomicAdd(&cursor[src[e]], 1);
    dst_s[pos] = dst[e];
    score_s[pos] = score[e];
  }
}

// per-node: softmax over segment scores, fp16 ass[dst] weighted sum,
// then fused gumbel-softmax epilogue writing the final output row.
__global__ __launch_bounds__(256) void node_aggregate_kernel(
    const float* __restrict__ score_s, const __half* __restrict__ ass,
    const int* __restrict__ start, const int* __restrict__ counts,
    const int* __restrict__ dst_s, float* __restrict__ out, int N) {
  int n = blockIdx.x * 4 + (threadIdx.x >> 6);
  if (n >= N) return;
  int lane = threadIdx.x & 63;
  int st = start[n], deg = counts[n];

  float m = -INFINITY;
  for (int i = lane; i < deg; i += 64) m = fmaxf(m, score_s[st + i]);
#pragma unroll
  for (int msk = 32; msk; msk >>= 1) m = fmaxf(m, __shfl_xor(m, msk));

  float ssum = 0.f;
  for (int i = lane; i < deg; i += 64) ssum += expf(score_s[st + i] - m);
#pragma unroll
  for (int msk = 32; msk; msk >>= 1) ssum += __shfl_xor(ssum, msk);
  float inv = 1.f / fmaxf(ssum, 1e-8f);

  // pass 3: software-pipelined gather-accumulate over fp16 ass rows
  float acc0 = 0.f, acc1 = 0.f;
  int c = lane * 2;
  int dnext = 0; float snext = 0.f;
  if (deg > 0) { dnext = dst_s[st]; snext = score_s[st]; }
  for (int i = 0; i < deg; ++i) {
    int dcur = dnext; float scur = snext;
    if (i + 1 < deg) { dnext = dst_s[st + i + 1]; snext = score_s[st + i + 1]; }
    float w = expf(scur - m) * inv;
    float2 v = __half22float2(
        *reinterpret_cast<const __half2*>(ass + (size_t)dcur * D128 + c));
    acc0 += w * v.x;
    acc1 += w * v.y;
  }

  // fused gumbel-softmax
  float v0, v1;
  {
    unsigned o0, o1;
    threefry2x32(0u, (unsigned)(n * D128 + c), o0, o1);
    unsigned bits = o0 ^ o1;
    float f = __uint_as_float((bits >> 9) | 0x3f800000u) - 1.0f;
    float u = fmaxf(1e-10f, f * (1.0f - 1e-10f) + 1e-10f);
    float g = -logf(-logf(u));
    v0 = (logf(acc0 + 1e-6f) + g) / 0.2f;
  }
  {
    unsigned o0, o1;
    threefry2x32(0u, (unsigned)(n * D128 + c + 1), o0, o1);
    unsigned bits = o0 ^ o1;
    float f = __uint_as_float((bits >> 9) | 0x3f800000u) - 1.0f;
    float u = fmaxf(1e-10f, f * (1.0f - 1e-10f) + 1e-10f);
    float g = -logf(-logf(u));
    v1 = (logf(acc1 + 1e-6f) + g) / 0.2f;
  }
  float mm = fmaxf(v0, v1);
#pragma unroll
  for (int msk = 32; msk; msk >>= 1) mm = fmaxf(mm, __shfl_xor(mm, msk));
  float e0 = expf(v0 - mm), e1 = expf(v1 - mm);
  float s = e0 + e1;
#pragma unroll
  for (int msk = 32; msk; msk >>= 1) s += __shfl_xor(s, msk);
  float invs = 1.f / s;
  *reinterpret_cast<float2*>(out + (size_t)n * D128 + c) =
      make_float2(e0 * invs, e1 * invs);
}

extern "C" void kernel_launch(void* const* d_in, const int* in_sizes, int n_in,
                              void* d_out, int out_size, void* d_ws, size_t ws_size,
                              hipStream_t stream) {
  const float* x   = (const float*)d_in[0];
  const int*   src = (const int*)d_in[1];
  const int*   dst = (const int*)d_in[2];
  // d_in[3] = edge_value (unused by reference)
  const float* Wq  = (const float*)d_in[4];
  const float* Wk  = (const float*)d_in[5];
  const float* Wa  = (const float*)d_in[6];
  const float* lsq = (const float*)d_in[7];
  const float* lsk = (const float*)d_in[8];
  const int N = in_sizes[0] / D128;
  const int E = in_sizes[1];
  float* out = (float*)d_out;

  float*  qbuf    = (float*)d_ws;
  float*  kbuf    = qbuf + (size_t)N * D128;
  __half* abuf    = (__half*)(kbuf + (size_t)N * D128);
  float*  score   = (float*)(abuf + (size_t)N * D128);
  int*    counts  = (int*)(score + E);
  int*    startv  = counts + N;
  int*    cursor  = startv + N;
  int*    partials= cursor + N;
  int*    dst_s   = partials + 256;
  float*  score_s = (float*)(dst_s + E);

  hipMemsetAsync(counts, 0, (size_t)N * sizeof(int), stream);

  const int gemm_blocks = (N + 31) / 32;
  gemm128_kernel<0, true ><<<gemm_blocks, 256, 0, stream>>>(x, Wa, nullptr,
                                                            (float*)abuf, N);
  gemm128_kernel<1, false><<<gemm_blocks, 256, 0, stream>>>(x, Wq, lsq, qbuf, N);
  gemm128_kernel<1, false><<<gemm_blocks, 256, 0, stream>>>(x, Wk, lsk, kbuf, N);

  edge_score_kernel<<<(E + 15) / 16, 256, 0, stream>>>(qbuf, kbuf, src, dst, score, counts, E);

  const int nb = (N + 255) / 256;
  scan1_kernel<<<nb, 256, 0, stream>>>(counts, startv, partials, N);
  scan2_kernel<<<1, 256, 0, stream>>>(partials, nb);
  scan3_kernel<<<nb, 256, 0, stream>>>(counts, startv, cursor, partials, N);
  csr_fill_kernel<<<(E + 255) / 256, 256, 0, stream>>>(src, dst, score, cursor,
                                                       dst_s, score_s, E);

  node_aggregate_kernel<<<(N + 3) / 4, 256, 0, stream>>>(score_s, abuf, startv,
                                                         counts, dst_s, out, N);
}

// Round 8
// 376.581 us; speedup vs baseline: 2.5003x; 1.0429x over previous
//
#include <hip/hip_runtime.h>
#include <hip/hip_bf16.h>
#include <hip/hip_fp16.h>
#include <math.h>

// ---------------------------------------------------------------------------
// LorentzAssignment on MI355X.
//   1-3. three fused 50000x128 @ 128x128 GEMMs (ass fp16 / q / k), 64-row
//        tiles, 4 rows/thread, W staged in LDS halves, skewed = conflict-free.
//   4. CSR build (count -> scan -> scatter dst_s).
//   5. node_fused: per-node online-softmax over -acosh Lorentz scores computed
//      on the fly (q row in registers), fp16 ass gather-accumulate, fused
//      gumbel-softmax epilogue. No edge score array is ever materialized.
// ---------------------------------------------------------------------------

#define D128 128

__device__ __forceinline__ void threefry2x32(unsigned x0, unsigned x1,
                                             unsigned& o0, unsigned& o1) {
  const unsigned k0 = 0u, k1 = 42u;
  const unsigned k2 = 0x1BD11BDAu ^ k0 ^ k1;
  x0 += k0; x1 += k1;
#define TF_ROT(r) { x0 += x1; x1 = (x1 << (r)) | (x1 >> (32 - (r))); x1 ^= x0; }
  TF_ROT(13) TF_ROT(15) TF_ROT(26) TF_ROT(6)
  x0 += k1; x1 += k2 + 1u;
  TF_ROT(17) TF_ROT(29) TF_ROT(16) TF_ROT(24)
  x0 += k2; x1 += k0 + 2u;
  TF_ROT(13) TF_ROT(15) TF_ROT(26) TF_ROT(6)
  x0 += k0; x1 += k1 + 3u;
  TF_ROT(17) TF_ROT(29) TF_ROT(16) TF_ROT(24)
  x0 += k1; x1 += k2 + 4u;
  TF_ROT(13) TF_ROT(15) TF_ROT(26) TF_ROT(6)
  x0 += k2; x1 += k0 + 5u;
#undef TF_ROT
  o0 = x0; o1 = x1;
}

// Skewed LDS addressing (float index of an aligned float4 chunk).
__device__ __forceinline__ int xaddr(int r, int k4) {
  return r * 128 + (((k4 + r) & 31) << 2);
}
__device__ __forceinline__ int waddr(int c, int k4) {
  return c * 64 + (((k4 + (c >> 3)) & 15) << 2);
}

// out = X @ W^T (N x 128, K=128), 64-row tile, 4 rows/thread.
// POST=0: row softmax -> fp16 out. POST=1: lorentz_linear tail -> fp32 out.
template <int POST, bool DO_LOGMAP>
__global__ __launch_bounds__(256) void gemm128_kernel(
    const float* __restrict__ X, const float* __restrict__ W,
    const float* __restrict__ ls, float* __restrict__ out, int N) {
  __shared__ float ws[128 * 64];   // 32 KB: one K-half of W, skewed
  __shared__ float xs[64 * 128];   // 32 KB: 64-row X tile, skewed

  const int t = threadIdx.x;
  const int row0 = blockIdx.x * 64;

  // ---- stage 64x128 X tile (zero-fill OOB rows), skewed ----
#pragma unroll
  for (int i = 0; i < 8; ++i) {
    int f = t + 256 * i;           // 2048 float4s
    int r = f >> 5, k4 = f & 31;
    float4 v = make_float4(0.f, 0.f, 0.f, 0.f);
    if (row0 + r < N)
      v = *reinterpret_cast<const float4*>(X + (size_t)(row0 + r) * D128 + k4 * 4);
    *reinterpret_cast<float4*>(&xs[xaddr(r, k4)]) = v;
  }
  __syncthreads();

  if (DO_LOGMAP) {
    // logmap0 in-place: row -> [0, d * narrow / ||narrow||]; 2 sweeps of 32 rows
#pragma unroll
    for (int rr = 0; rr < 2; ++rr) {
      int r = (t >> 3) + 32 * rr, tr = t & 7;
      float ss = 0.f;
      float4 ch[4];
#pragma unroll
      for (int i = 0; i < 4; ++i) {
        ch[i] = *reinterpret_cast<float4*>(&xs[xaddr(r, tr + 8 * i)]);
        ss += ch[i].x * ch[i].x + ch[i].y * ch[i].y + ch[i].z * ch[i].z + ch[i].w * ch[i].w;
      }
      if (tr == 0) ss -= ch[0].x * ch[0].x;
#pragma unroll
      for (int msk = 1; msk < 8; msk <<= 1) ss += __shfl_xor(ss, msk);
      float x0v = __shfl(ch[0].x, (t & 63) & ~7);
      float dd = acoshf(fmaxf(x0v, 1.f + 1e-6f));
      float sc = dd / fmaxf(sqrtf(ss), 1e-8f);
#pragma unroll
      for (int i = 0; i < 4; ++i) {
        float4 v = ch[i];
        v.x *= sc; v.y *= sc; v.z *= sc; v.w *= sc;
        if (tr == 0 && i == 0) v.x = 0.f;
        *reinterpret_cast<float4*>(&xs[xaddr(r, tr + 8 * i)]) = v;
      }
    }
    __syncthreads();
  }

  const int cg = t & 15;           // col group: cols 8cg..8cg+7
  const int rg = t >> 4;           // rows rg + 16m, m=0..3
  float acc[4][8];
#pragma unroll
  for (int m = 0; m < 4; ++m)
#pragma unroll
    for (int j = 0; j < 8; ++j) acc[m][j] = 0.f;

  for (int h = 0; h < 2; ++h) {
    if (h) __syncthreads();
#pragma unroll
    for (int i = 0; i < 8; ++i) {
      int f = t + 256 * i;
      int c = f >> 4, k4 = f & 15;
      float4 v = *reinterpret_cast<const float4*>(W + (size_t)c * D128 + h * 64 + k4 * 4);
      *reinterpret_cast<float4*>(&ws[waddr(c, k4)]) = v;
    }
    __syncthreads();

#pragma unroll 4
    for (int kk = 0; kk < 16; ++kk) {
      int xk4 = h * 16 + kk;
      float4 xv[4];
#pragma unroll
      for (int m = 0; m < 4; ++m)
        xv[m] = *reinterpret_cast<const float4*>(&xs[xaddr(rg + 16 * m, xk4)]);
#pragma unroll
      for (int j = 0; j < 8; ++j) {
        float4 w4 = *reinterpret_cast<const float4*>(&ws[waddr(cg * 8 + j, kk)]);
#pragma unroll
        for (int m = 0; m < 4; ++m)
          acc[m][j] += xv[m].x * w4.x + xv[m].y * w4.y + xv[m].z * w4.z + xv[m].w * w4.w;
      }
    }
  }

  const int lane = t & 63;
  const int gbase = lane & ~15;

  if (POST == 0) {
    __half* oh = reinterpret_cast<__half*>(out);
#pragma unroll
    for (int m = 0; m < 4; ++m) {
      float mx = acc[m][0];
#pragma unroll
      for (int j = 1; j < 8; ++j) mx = fmaxf(mx, acc[m][j]);
#pragma unroll
      for (int msk = 1; msk < 16; msk <<= 1) mx = fmaxf(mx, __shfl_xor(mx, msk));
      float sm = 0.f;
#pragma unroll
      for (int j = 0; j < 8; ++j) { acc[m][j] = expf(acc[m][j] - mx); sm += acc[m][j]; }
#pragma unroll
      for (int msk = 1; msk < 16; msk <<= 1) sm += __shfl_xor(sm, msk);
      float inv = 1.f / sm;
      int gr = row0 + rg + 16 * m;
      if (gr < N) {
        union { __half2 h2[4]; uint4 u; } pk;
        pk.h2[0] = __floats2half2_rn(acc[m][0] * inv, acc[m][1] * inv);
        pk.h2[1] = __floats2half2_rn(acc[m][2] * inv, acc[m][3] * inv);
        pk.h2[2] = __floats2half2_rn(acc[m][4] * inv, acc[m][5] * inv);
        pk.h2[3] = __floats2half2_rn(acc[m][6] * inv, acc[m][7] * inv);
        *reinterpret_cast<uint4*>(oh + (size_t)gr * D128 + cg * 8) = pk.u;
      }
    }
  } else {
    float scale = expf(ls[0]);
#pragma unroll
    for (int m = 0; m < 4; ++m) {
      float ss = 0.f;
#pragma unroll
      for (int j = 0; j < 8; ++j) {
        float v = acc[m][j];
        if (cg == 0 && j == 0) v = 0.f;
        ss += v * v;
      }
#pragma unroll
      for (int msk = 1; msk < 16; msk <<= 1) ss += __shfl_xor(ss, msk);
      float y0 = __shfl(acc[m][0], gbase);
      float tm = scale / (1.f + expf(-y0)) + 1.1f;
      float qs = sqrtf((tm * tm - 1.f) / fmaxf(ss, 1e-8f));
      int gr = row0 + rg + 16 * m;
      if (gr < N) {
        float o[8];
#pragma unroll
        for (int j = 0; j < 8; ++j) o[j] = acc[m][j] * qs;
        if (cg == 0) o[0] = tm;
        *reinterpret_cast<float4*>(out + (size_t)gr * D128 + cg * 8) =
            make_float4(o[0], o[1], o[2], o[3]);
        *reinterpret_cast<float4*>(out + (size_t)gr * D128 + cg * 8 + 4) =
            make_float4(o[4], o[5], o[6], o[7]);
      }
    }
  }
}

// counts[src[e]]++
__global__ __launch_bounds__(256) void count_kernel(const int* __restrict__ src,
                                                    int* __restrict__ counts, int E) {
  int e = blockIdx.x * 256 + threadIdx.x;
  if (e < E) atomicAdd(&counts[src[e]], 1);
}

// --- 3-kernel exclusive scan of counts -> start, cursor ---
__global__ __launch_bounds__(256) void scan1_kernel(const int* __restrict__ counts,
                                                    int* __restrict__ incl,
                                                    int* __restrict__ partials, int N) {
  int i = blockIdx.x * 256 + threadIdx.x;
  int c = (i < N) ? counts[i] : 0;
  int lane = threadIdx.x & 63, w = threadIdx.x >> 6;
  int v = c;
#pragma unroll
  for (int d = 1; d < 64; d <<= 1) {
    int tv = __shfl_up(v, d);
    if (lane >= d) v += tv;
  }
  __shared__ int wsum[4];
  if (lane == 63) wsum[w] = v;
  __syncthreads();
  int add = 0;
  for (int j = 0; j < w; ++j) add += wsum[j];
  v += add;
  if (i < N) incl[i] = v;
  if (threadIdx.x == 255) partials[blockIdx.x] = v;
}

__global__ __launch_bounds__(256) void scan2_kernel(int* __restrict__ partials, int nparts) {
  int t = threadIdx.x;
  int p = (t < nparts) ? partials[t] : 0;
  int lane = t & 63, w = t >> 6;
  int v = p;
#pragma unroll
  for (int d = 1; d < 64; d <<= 1) {
    int tv = __shfl_up(v, d);
    if (lane >= d) v += tv;
  }
  __shared__ int wsum[4];
  if (lane == 63) wsum[w] = v;
  __syncthreads();
  int add = 0;
  for (int j = 0; j < w; ++j) add += wsum[j];
  v += add;
  if (t < nparts) partials[t] = v - p;
}

__global__ __launch_bounds__(256) void scan3_kernel(const int* __restrict__ counts,
                                                    int* __restrict__ incl_to_start,
                                                    int* __restrict__ cursor,
                                                    const int* __restrict__ partials, int N) {
  int i = blockIdx.x * 256 + threadIdx.x;
  if (i < N) {
    int s = incl_to_start[i] - counts[i] + partials[blockIdx.x];
    incl_to_start[i] = s;
    cursor[i] = s;
  }
}

// scatter dst into CSR (segment-sorted) order
__global__ __launch_bounds__(256) void csr_fill_kernel(
    const int* __restrict__ src, const int* __restrict__ dst,
    int* __restrict__ cursor, int* __restrict__ dst_s, int E) {
  int e = blockIdx.x * 256 + threadIdx.x;
  if (e < E) {
    int pos = atomicAdd(&cursor[src[e]], 1);
    dst_s[pos] = dst[e];
  }
}

// One 16-lane group per node: q row in registers; per edge compute
// -acosh(<q,k[dst]>_L) (4-step shuffle reduce), online-softmax rescale,
// fp16 ass[dst] accumulate; fused gumbel-softmax epilogue.
__global__ __launch_bounds__(256) void node_fused_kernel(
    const float* __restrict__ q, const float* __restrict__ k,
    const __half* __restrict__ ass, const int* __restrict__ start,
    const int* __restrict__ counts, const int* __restrict__ dst_s,
    float* __restrict__ out, int N) {
  int g = threadIdx.x >> 4;        // 16 groups per block
  int lq = threadIdx.x & 15;
  int n = blockIdx.x * 16 + g;
  if (n >= N) return;
  int st = start[n], deg = counts[n];
  int c8 = lq * 8;

  float4 qa = *reinterpret_cast<const float4*>(q + (size_t)n * D128 + c8);
  float4 qb = *reinterpret_cast<const float4*>(q + (size_t)n * D128 + c8 + 4);

  float m = -INFINITY, lsum = 0.f;
  float acc[8];
#pragma unroll
  for (int j = 0; j < 8; ++j) acc[j] = 0.f;

  if (deg > 0) {
    // 2-deep pipeline: cur loaded, next index known
    int d_cur = dst_s[st];
    int d_nxt = (deg > 1) ? dst_s[st + 1] : d_cur;
    float4 ka = *reinterpret_cast<const float4*>(k + (size_t)d_cur * D128 + c8);
    float4 kb = *reinterpret_cast<const float4*>(k + (size_t)d_cur * D128 + c8 + 4);
    uint4 av = *reinterpret_cast<const uint4*>(ass + (size_t)d_cur * D128 + c8);

    for (int i = 0; i < deg; ++i) {
      // issue next-edge loads before computing current
      float4 ka_n = *reinterpret_cast<const float4*>(k + (size_t)d_nxt * D128 + c8);
      float4 kb_n = *reinterpret_cast<const float4*>(k + (size_t)d_nxt * D128 + c8 + 4);
      uint4 av_n = *reinterpret_cast<const uint4*>(ass + (size_t)d_nxt * D128 + c8);
      int p2 = st + i + 2;
      int d_nn = dst_s[(p2 < st + deg) ? p2 : st];

      // signed partial: lane0 contributes q0k0 - rest, others -(dot)
      float part = qa.x * ka.x + qa.y * ka.y + qa.z * ka.z + qa.w * ka.w +
                   qb.x * kb.x + qb.y * kb.y + qb.z * kb.z + qb.w * kb.w;
      part = (lq == 0) ? (2.f * qa.x * ka.x - part) : (-part);
#pragma unroll
      for (int msk = 1; msk < 16; msk <<= 1) part += __shfl_xor(part, msk);
      float s = -acoshf(fmaxf(part, 1.f + 1e-6f));

      float mn = fmaxf(m, s);
      float corr = expf(m - mn);     // first iter: exp(-inf)=0
      float w = expf(s - mn);
      lsum = lsum * corr + w;
      const __half2* hp = reinterpret_cast<const __half2*>(&av);
      float2 v0 = __half22float2(hp[0]);
      float2 v1 = __half22float2(hp[1]);
      float2 v2 = __half22float2(hp[2]);
      float2 v3 = __half22float2(hp[3]);
      acc[0] = acc[0] * corr + w * v0.x;  acc[1] = acc[1] * corr + w * v0.y;
      acc[2] = acc[2] * corr + w * v1.x;  acc[3] = acc[3] * corr + w * v1.y;
      acc[4] = acc[4] * corr + w * v2.x;  acc[5] = acc[5] * corr + w * v2.y;
      acc[6] = acc[6] * corr + w * v3.x;  acc[7] = acc[7] * corr + w * v3.y;
      m = mn;

      ka = ka_n; kb = kb_n; av = av_n;
      d_nxt = d_nn;
    }
  }

  float inv = (deg > 0) ? 1.f / fmaxf(lsum, 1e-8f) : 0.f;

  // fused gumbel-softmax over the 128-dim row (16 lanes x 8 dims)
  float vg[8];
#pragma unroll
  for (int j = 0; j < 8; ++j) {
    unsigned o0, o1;
    threefry2x32(0u, (unsigned)(n * D128 + c8 + j), o0, o1);
    unsigned bits = o0 ^ o1;
    float f = __uint_as_float((bits >> 9) | 0x3f800000u) - 1.0f;
    float u = fmaxf(1e-10f, f * (1.0f - 1e-10f) + 1e-10f);
    float gmb = -logf(-logf(u));
    vg[j] = (logf(acc[j] * inv + 1e-6f) + gmb) / 0.2f;
  }
  float mm = vg[0];
#pragma unroll
  for (int j = 1; j < 8; ++j) mm = fmaxf(mm, vg[j]);
#pragma unroll
  for (int msk = 1; msk < 16; msk <<= 1) mm = fmaxf(mm, __shfl_xor(mm, msk));
  float sm = 0.f;
#pragma unroll
  for (int j = 0; j < 8; ++j) { vg[j] = expf(vg[j] - mm); sm += vg[j]; }
#pragma unroll
  for (int msk = 1; msk < 16; msk <<= 1) sm += __shfl_xor(sm, msk);
  float invs = 1.f / sm;
  *reinterpret_cast<float4*>(out + (size_t)n * D128 + c8) =
      make_float4(vg[0] * invs, vg[1] * invs, vg[2] * invs, vg[3] * invs);
  *reinterpret_cast<float4*>(out + (size_t)n * D128 + c8 + 4) =
      make_float4(vg[4] * invs, vg[5] * invs, vg[6] * invs, vg[7] * invs);
}

extern "C" void kernel_launch(void* const* d_in, const int* in_sizes, int n_in,
                              void* d_out, int out_size, void* d_ws, size_t ws_size,
                              hipStream_t stream) {
  const float* x   = (const float*)d_in[0];
  const int*   src = (const int*)d_in[1];
  const int*   dst = (const int*)d_in[2];
  // d_in[3] = edge_value (unused by reference)
  const float* Wq  = (const float*)d_in[4];
  const float* Wk  = (const float*)d_in[5];
  const float* Wa  = (const float*)d_in[6];
  const float* lsq = (const float*)d_in[7];
  const float* lsk = (const float*)d_in[8];
  const int N = in_sizes[0] / D128;
  const int E = in_sizes[1];
  float* out = (float*)d_out;

  float*  qbuf    = (float*)d_ws;
  float*  kbuf    = qbuf + (size_t)N * D128;
  __half* abuf    = (__half*)(kbuf + (size_t)N * D128);
  int*    counts  = (int*)(abuf + (size_t)N * D128);
  int*    startv  = counts + N;
  int*    cursor  = startv + N;
  int*    partials= cursor + N;
  int*    dst_s   = partials + 256;

  hipMemsetAsync(counts, 0, (size_t)N * sizeof(int), stream);

  const int gemm_blocks = (N + 63) / 64;
  gemm128_kernel<0, true ><<<gemm_blocks, 256, 0, stream>>>(x, Wa, nullptr,
                                                            (float*)abuf, N);
  gemm128_kernel<1, false><<<gemm_blocks, 256, 0, stream>>>(x, Wq, lsq, qbuf, N);
  gemm128_kernel<1, false><<<gemm_blocks, 256, 0, stream>>>(x, Wk, lsk, kbuf, N);

  const int eb = (E + 255) / 256;
  count_kernel<<<eb, 256, 0, stream>>>(src, counts, E);

  const int nb = (N + 255) / 256;
  scan1_kernel<<<nb, 256, 0, stream>>>(counts, startv, partials, N);
  scan2_kernel<<<1, 256, 0, stream>>>(partials, nb);
  scan3_kernel<<<nb, 256, 0, stream>>>(counts, startv, cursor, partials, N);
  csr_fill_kernel<<<eb, 256, 0, stream>>>(src, dst, cursor, dst_s, E);

  node_fused_kernel<<<(N + 15) / 16, 256, 0, stream>>>(qbuf, kbuf, abuf, startv,
                                                       counts, dst_s, out, N);
}

// Round 9
// 345.028 us; speedup vs baseline: 2.7289x; 1.0915x over previous
//
#include <hip/hip_runtime.h>
#include <hip/hip_bf16.h>
#include <hip/hip_fp16.h>
#include <math.h>

// ---------------------------------------------------------------------------
// LorentzAssignment on MI355X.
//   1-3. three fused 50000x128 @ 128x128 GEMMs (ass fp16 / q / k), 64-row
//        tiles, 4 rows/thread, W staged in LDS halves, skewed = conflict-free.
//   4. CSR build (count -> scan -> scatter dst_s).
//   5. node_fused: per-node softmax over Lorentz scores via the CLOSED FORM
//      exp(-acosh(x)) = 1/(x+sqrt(x^2-1))  (scores <= 0 so no max tracking),
//      fp16 ass gather-accumulate, fused gumbel-softmax epilogue.
// ---------------------------------------------------------------------------

#define D128 128

__device__ __forceinline__ void threefry2x32(unsigned x0, unsigned x1,
                                             unsigned& o0, unsigned& o1) {
  const unsigned k0 = 0u, k1 = 42u;
  const unsigned k2 = 0x1BD11BDAu ^ k0 ^ k1;
  x0 += k0; x1 += k1;
#define TF_ROT(r) { x0 += x1; x1 = (x1 << (r)) | (x1 >> (32 - (r))); x1 ^= x0; }
  TF_ROT(13) TF_ROT(15) TF_ROT(26) TF_ROT(6)
  x0 += k1; x1 += k2 + 1u;
  TF_ROT(17) TF_ROT(29) TF_ROT(16) TF_ROT(24)
  x0 += k2; x1 += k0 + 2u;
  TF_ROT(13) TF_ROT(15) TF_ROT(26) TF_ROT(6)
  x0 += k0; x1 += k1 + 3u;
  TF_ROT(17) TF_ROT(29) TF_ROT(16) TF_ROT(24)
  x0 += k1; x1 += k2 + 4u;
  TF_ROT(13) TF_ROT(15) TF_ROT(26) TF_ROT(6)
  x0 += k2; x1 += k0 + 5u;
#undef TF_ROT
  o0 = x0; o1 = x1;
}

// Skewed LDS addressing (float index of an aligned float4 chunk).
__device__ __forceinline__ int xaddr(int r, int k4) {
  return r * 128 + (((k4 + r) & 31) << 2);
}
__device__ __forceinline__ int waddr(int c, int k4) {
  return c * 64 + (((k4 + (c >> 3)) & 15) << 2);
}

// out = X @ W^T (N x 128, K=128), 64-row tile, 4 rows/thread.
// POST=0: row softmax -> fp16 out. POST=1: lorentz_linear tail -> fp32 out.
template <int POST, bool DO_LOGMAP>
__global__ __launch_bounds__(256) void gemm128_kernel(
    const float* __restrict__ X, const float* __restrict__ W,
    const float* __restrict__ ls, float* __restrict__ out, int N) {
  __shared__ float ws[128 * 64];   // 32 KB: one K-half of W, skewed
  __shared__ float xs[64 * 128];   // 32 KB: 64-row X tile, skewed

  const int t = threadIdx.x;
  const int row0 = blockIdx.x * 64;

#pragma unroll
  for (int i = 0; i < 8; ++i) {
    int f = t + 256 * i;
    int r = f >> 5, k4 = f & 31;
    float4 v = make_float4(0.f, 0.f, 0.f, 0.f);
    if (row0 + r < N)
      v = *reinterpret_cast<const float4*>(X + (size_t)(row0 + r) * D128 + k4 * 4);
    *reinterpret_cast<float4*>(&xs[xaddr(r, k4)]) = v;
  }
  __syncthreads();

  if (DO_LOGMAP) {
#pragma unroll
    for (int rr = 0; rr < 2; ++rr) {
      int r = (t >> 3) + 32 * rr, tr = t & 7;
      float ss = 0.f;
      float4 ch[4];
#pragma unroll
      for (int i = 0; i < 4; ++i) {
        ch[i] = *reinterpret_cast<float4*>(&xs[xaddr(r, tr + 8 * i)]);
        ss += ch[i].x * ch[i].x + ch[i].y * ch[i].y + ch[i].z * ch[i].z + ch[i].w * ch[i].w;
      }
      if (tr == 0) ss -= ch[0].x * ch[0].x;
#pragma unroll
      for (int msk = 1; msk < 8; msk <<= 1) ss += __shfl_xor(ss, msk);
      float x0v = __shfl(ch[0].x, (t & 63) & ~7);
      float dd = acoshf(fmaxf(x0v, 1.f + 1e-6f));
      float sc = dd / fmaxf(sqrtf(ss), 1e-8f);
#pragma unroll
      for (int i = 0; i < 4; ++i) {
        float4 v = ch[i];
        v.x *= sc; v.y *= sc; v.z *= sc; v.w *= sc;
        if (tr == 0 && i == 0) v.x = 0.f;
        *reinterpret_cast<float4*>(&xs[xaddr(r, tr + 8 * i)]) = v;
      }
    }
    __syncthreads();
  }

  const int cg = t & 15;
  const int rg = t >> 4;
  float acc[4][8];
#pragma unroll
  for (int m = 0; m < 4; ++m)
#pragma unroll
    for (int j = 0; j < 8; ++j) acc[m][j] = 0.f;

  for (int h = 0; h < 2; ++h) {
    if (h) __syncthreads();
#pragma unroll
    for (int i = 0; i < 8; ++i) {
      int f = t + 256 * i;
      int c = f >> 4, k4 = f & 15;
      float4 v = *reinterpret_cast<const float4*>(W + (size_t)c * D128 + h * 64 + k4 * 4);
      *reinterpret_cast<float4*>(&ws[waddr(c, k4)]) = v;
    }
    __syncthreads();

#pragma unroll 4
    for (int kk = 0; kk < 16; ++kk) {
      int xk4 = h * 16 + kk;
      float4 xv[4];
#pragma unroll
      for (int m = 0; m < 4; ++m)
        xv[m] = *reinterpret_cast<const float4*>(&xs[xaddr(rg + 16 * m, xk4)]);
#pragma unroll
      for (int j = 0; j < 8; ++j) {
        float4 w4 = *reinterpret_cast<const float4*>(&ws[waddr(cg * 8 + j, kk)]);
#pragma unroll
        for (int m = 0; m < 4; ++m)
          acc[m][j] += xv[m].x * w4.x + xv[m].y * w4.y + xv[m].z * w4.z + xv[m].w * w4.w;
      }
    }
  }

  const int lane = t & 63;
  const int gbase = lane & ~15;

  if (POST == 0) {
    __half* oh = reinterpret_cast<__half*>(out);
#pragma unroll
    for (int m = 0; m < 4; ++m) {
      float mx = acc[m][0];
#pragma unroll
      for (int j = 1; j < 8; ++j) mx = fmaxf(mx, acc[m][j]);
#pragma unroll
      for (int msk = 1; msk < 16; msk <<= 1) mx = fmaxf(mx, __shfl_xor(mx, msk));
      float sm = 0.f;
#pragma unroll
      for (int j = 0; j < 8; ++j) { acc[m][j] = expf(acc[m][j] - mx); sm += acc[m][j]; }
#pragma unroll
      for (int msk = 1; msk < 16; msk <<= 1) sm += __shfl_xor(sm, msk);
      float inv = 1.f / sm;
      int gr = row0 + rg + 16 * m;
      if (gr < N) {
        union { __half2 h2[4]; uint4 u; } pk;
        pk.h2[0] = __floats2half2_rn(acc[m][0] * inv, acc[m][1] * inv);
        pk.h2[1] = __floats2half2_rn(acc[m][2] * inv, acc[m][3] * inv);
        pk.h2[2] = __floats2half2_rn(acc[m][4] * inv, acc[m][5] * inv);
        pk.h2[3] = __floats2half2_rn(acc[m][6] * inv, acc[m][7] * inv);
        *reinterpret_cast<uint4*>(oh + (size_t)gr * D128 + cg * 8) = pk.u;
      }
    }
  } else {
    float scale = expf(ls[0]);
#pragma unroll
    for (int m = 0; m < 4; ++m) {
      float ss = 0.f;
#pragma unroll
      for (int j = 0; j < 8; ++j) {
        float v = acc[m][j];
        if (cg == 0 && j == 0) v = 0.f;
        ss += v * v;
      }
#pragma unroll
      for (int msk = 1; msk < 16; msk <<= 1) ss += __shfl_xor(ss, msk);
      float y0 = __shfl(acc[m][0], gbase);
      float tm = scale / (1.f + expf(-y0)) + 1.1f;
      float qs = sqrtf((tm * tm - 1.f) / fmaxf(ss, 1e-8f));
      int gr = row0 + rg + 16 * m;
      if (gr < N) {
        float o[8];
#pragma unroll
        for (int j = 0; j < 8; ++j) o[j] = acc[m][j] * qs;
        if (cg == 0) o[0] = tm;
        *reinterpret_cast<float4*>(out + (size_t)gr * D128 + cg * 8) =
            make_float4(o[0], o[1], o[2], o[3]);
        *reinterpret_cast<float4*>(out + (size_t)gr * D128 + cg * 8 + 4) =
            make_float4(o[4], o[5], o[6], o[7]);
      }
    }
  }
}

// counts[src[e]]++
__global__ __launch_bounds__(256) void count_kernel(const int* __restrict__ src,
                                                    int* __restrict__ counts, int E) {
  int e = blockIdx.x * 256 + threadIdx.x;
  if (e < E) atomicAdd(&counts[src[e]], 1);
}

// --- 3-kernel exclusive scan of counts -> start, cursor ---
__global__ __launch_bounds__(256) void scan1_kernel(const int* __restrict__ counts,
                                                    int* __restrict__ incl,
                                                    int* __restrict__ partials, int N) {
  int i = blockIdx.x * 256 + threadIdx.x;
  int c = (i < N) ? counts[i] : 0;
  int lane = threadIdx.x & 63, w = threadIdx.x >> 6;
  int v = c;
#pragma unroll
  for (int d = 1; d < 64; d <<= 1) {
    int tv = __shfl_up(v, d);
    if (lane >= d) v += tv;
  }
  __shared__ int wsum[4];
  if (lane == 63) wsum[w] = v;
  __syncthreads();
  int add = 0;
  for (int j = 0; j < w; ++j) add += wsum[j];
  v += add;
  if (i < N) incl[i] = v;
  if (threadIdx.x == 255) partials[blockIdx.x] = v;
}

__global__ __launch_bounds__(256) void scan2_kernel(int* __restrict__ partials, int nparts) {
  int t = threadIdx.x;
  int p = (t < nparts) ? partials[t] : 0;
  int lane = t & 63, w = t >> 6;
  int v = p;
#pragma unroll
  for (int d = 1; d < 64; d <<= 1) {
    int tv = __shfl_up(v, d);
    if (lane >= d) v += tv;
  }
  __shared__ int wsum[4];
  if (lane == 63) wsum[w] = v;
  __syncthreads();
  int add = 0;
  for (int j = 0; j < w; ++j) add += wsum[j];
  v += add;
  if (t < nparts) partials[t] = v - p;
}

__global__ __launch_bounds__(256) void scan3_kernel(const int* __restrict__ counts,
                                                    int* __restrict__ incl_to_start,
                                                    int* __restrict__ cursor,
                                                    const int* __restrict__ partials, int N) {
  int i = blockIdx.x * 256 + threadIdx.x;
  if (i < N) {
    int s = incl_to_start[i] - counts[i] + partials[blockIdx.x];
    incl_to_start[i] = s;
    cursor[i] = s;
  }
}

// scatter dst into CSR (segment-sorted) order
__global__ __launch_bounds__(256) void csr_fill_kernel(
    const int* __restrict__ src, const int* __restrict__ dst,
    int* __restrict__ cursor, int* __restrict__ dst_s, int E) {
  int e = blockIdx.x * 256 + threadIdx.x;
  if (e < E) {
    int pos = atomicAdd(&cursor[src[e]], 1);
    dst_s[pos] = dst[e];
  }
}

// One 16-lane group per node: q row in registers; per edge the softmax weight
// w = exp(-acosh(x)) = 1/(x+sqrt(x^2-1)) in closed form (no acosh/exp, no
// max tracking since scores <= 0); accumulate sum(w), sum(w*ass[dst]);
// fused gumbel-softmax epilogue.
__global__ __launch_bounds__(256) void node_fused_kernel(
    const float* __restrict__ q, const float* __restrict__ k,
    const __half* __restrict__ ass, const int* __restrict__ start,
    const int* __restrict__ counts, const int* __restrict__ dst_s,
    float* __restrict__ out, int N) {
  int g = threadIdx.x >> 4;        // 16 groups per block
  int lq = threadIdx.x & 15;
  int n = blockIdx.x * 16 + g;
  if (n >= N) return;
  int st = start[n], deg = counts[n];
  int c8 = lq * 8;

  float4 qa = *reinterpret_cast<const float4*>(q + (size_t)n * D128 + c8);
  float4 qb = *reinterpret_cast<const float4*>(q + (size_t)n * D128 + c8 + 4);

  float lsum = 0.f;
  float acc[8];
#pragma unroll
  for (int j = 0; j < 8; ++j) acc[j] = 0.f;

  if (deg > 0) {
    // 2-deep pipeline: cur loaded, next index known
    int d_cur = dst_s[st];
    int d_nxt = (deg > 1) ? dst_s[st + 1] : d_cur;
    float4 ka = *reinterpret_cast<const float4*>(k + (size_t)d_cur * D128 + c8);
    float4 kb = *reinterpret_cast<const float4*>(k + (size_t)d_cur * D128 + c8 + 4);
    uint4 av = *reinterpret_cast<const uint4*>(ass + (size_t)d_cur * D128 + c8);

    for (int i = 0; i < deg; ++i) {
      // issue next-edge loads before computing current
      float4 ka_n = *reinterpret_cast<const float4*>(k + (size_t)d_nxt * D128 + c8);
      float4 kb_n = *reinterpret_cast<const float4*>(k + (size_t)d_nxt * D128 + c8 + 4);
      uint4 av_n = *reinterpret_cast<const uint4*>(ass + (size_t)d_nxt * D128 + c8);
      int p2 = st + i + 2;
      int d_nn = dst_s[(p2 < st + deg) ? p2 : st];

      // signed partial: lane0 contributes q0k0 - rest, others -(dot)
      float part = qa.x * ka.x + qa.y * ka.y + qa.z * ka.z + qa.w * ka.w +
                   qb.x * kb.x + qb.y * kb.y + qb.z * kb.z + qb.w * kb.w;
      part = (lq == 0) ? (2.f * qa.x * ka.x - part) : (-part);
#pragma unroll
      for (int msk = 1; msk < 16; msk <<= 1) part += __shfl_xor(part, msk);

      // w = exp(-acosh(x)) = 1/(x + sqrt(x^2-1)), x clipped to 1+1e-6
      float x = fmaxf(part, 1.f + 1e-6f);
      float t = x + sqrtf(__builtin_fmaf(x, x, -1.f));
      float w = __builtin_amdgcn_rcpf(t);

      lsum += w;
      const __half2* hp = reinterpret_cast<const __half2*>(&av);
      float2 v0 = __half22float2(hp[0]);
      float2 v1 = __half22float2(hp[1]);
      float2 v2 = __half22float2(hp[2]);
      float2 v3 = __half22float2(hp[3]);
      acc[0] += w * v0.x;  acc[1] += w * v0.y;
      acc[2] += w * v1.x;  acc[3] += w * v1.y;
      acc[4] += w * v2.x;  acc[5] += w * v2.y;
      acc[6] += w * v3.x;  acc[7] += w * v3.y;

      ka = ka_n; kb = kb_n; av = av_n;
      d_nxt = d_nn;
    }
  }

  float inv = (deg > 0) ? 1.f / fmaxf(lsum, 1e-8f) : 0.f;

  // fused gumbel-softmax over the 128-dim row (16 lanes x 8 dims)
  float vg[8];
#pragma unroll
  for (int j = 0; j < 8; ++j) {
    unsigned o0, o1;
    threefry2x32(0u, (unsigned)(n * D128 + c8 + j), o0, o1);
    unsigned bits = o0 ^ o1;
    float f = __uint_as_float((bits >> 9) | 0x3f800000u) - 1.0f;
    float u = fmaxf(1e-10f, f * (1.0f - 1e-10f) + 1e-10f);
    float gmb = -logf(-logf(u));
    vg[j] = (logf(acc[j] * inv + 1e-6f) + gmb) / 0.2f;
  }
  float mm = vg[0];
#pragma unroll
  for (int j = 1; j < 8; ++j) mm = fmaxf(mm, vg[j]);
#pragma unroll
  for (int msk = 1; msk < 16; msk <<= 1) mm = fmaxf(mm, __shfl_xor(mm, msk));
  float sm = 0.f;
#pragma unroll
  for (int j = 0; j < 8; ++j) { vg[j] = expf(vg[j] - mm); sm += vg[j]; }
#pragma unroll
  for (int msk = 1; msk < 16; msk <<= 1) sm += __shfl_xor(sm, msk);
  float invs = 1.f / sm;
  *reinterpret_cast<float4*>(out + (size_t)n * D128 + c8) =
      make_float4(vg[0] * invs, vg[1] * invs, vg[2] * invs, vg[3] * invs);
  *reinterpret_cast<float4*>(out + (size_t)n * D128 + c8 + 4) =
      make_float4(vg[4] * invs, vg[5] * invs, vg[6] * invs, vg[7] * invs);
}

extern "C" void kernel_launch(void* const* d_in, const int* in_sizes, int n_in,
                              void* d_out, int out_size, void* d_ws, size_t ws_size,
                              hipStream_t stream) {
  const float* x   = (const float*)d_in[0];
  const int*   src = (const int*)d_in[1];
  const int*   dst = (const int*)d_in[2];
  // d_in[3] = edge_value (unused by reference)
  const float* Wq  = (const float*)d_in[4];
  const float* Wk  = (const float*)d_in[5];
  const float* Wa  = (const float*)d_in[6];
  const float* lsq = (const float*)d_in[7];
  const float* lsk = (const float*)d_in[8];
  const int N = in_sizes[0] / D128;
  const int E = in_sizes[1];
  float* out = (float*)d_out;

  float*  qbuf    = (float*)d_ws;
  float*  kbuf    = qbuf + (size_t)N * D128;
  __half* abuf    = (__half*)(kbuf + (size_t)N * D128);
  int*    counts  = (int*)(abuf + (size_t)N * D128);
  int*    startv  = counts + N;
  int*    cursor  = startv + N;
  int*    partials= cursor + N;
  int*    dst_s   = partials + 256;

  hipMemsetAsync(counts, 0, (size_t)N * sizeof(int), stream);

  const int gemm_blocks = (N + 63) / 64;
  gemm128_kernel<0, true ><<<gemm_blocks, 256, 0, stream>>>(x, Wa, nullptr,
                                                            (float*)abuf, N);
  gemm128_kernel<1, false><<<gemm_blocks, 256, 0, stream>>>(x, Wq, lsq, qbuf, N);
  gemm128_kernel<1, false><<<gemm_blocks, 256, 0, stream>>>(x, Wk, lsk, kbuf, N);

  const int eb = (E + 255) / 256;
  count_kernel<<<eb, 256, 0, stream>>>(src, counts, E);

  const int nb = (N + 255) / 256;
  scan1_kernel<<<nb, 256, 0, stream>>>(counts, startv, partials, N);
  scan2_kernel<<<1, 256, 0, stream>>>(partials, nb);
  scan3_kernel<<<nb, 256, 0, stream>>>(counts, startv, cursor, partials, N);
  csr_fill_kernel<<<eb, 256, 0, stream>>>(src, dst, cursor, dst_s, E);

  node_fused_kernel<<<(N + 15) / 16, 256, 0, stream>>>(qbuf, kbuf, abuf, startv,
                                                       counts, dst_s, out, N);
}

// Round 10
// 225.052 us; speedup vs baseline: 4.1837x; 1.5331x over previous
//
#include <hip/hip_runtime.h>
#include <hip/hip_bf16.h>
#include <hip/hip_fp16.h>
#include <math.h>

// ---------------------------------------------------------------------------
// LorentzAssignment on MI355X.
//   1. gemm_ass: logmap0(x) @ Wa^T via fp16 MFMA (fp32 accum), softmax, fp16 out
//   2. gemm_qk : x @ Wq^T and x @ Wk^T from ONE X staging, lorentz tail,
//                q -> fp32, k -> fp16
//   3. CSR build (count -> scan -> scatter dst_s)
//   4. node_fused: per-node closed-form softmax w = 1/(x+sqrt(x^2-1)) over
//      Lorentz scores, fp16 k + fp16 ass gathers, fused gumbel-softmax.
// ---------------------------------------------------------------------------

#define D128 128
#define XP 136                    // padded fp16 row length (136*2=272B, 272%16==0)

typedef _Float16 f16x8 __attribute__((ext_vector_type(8)));
typedef float f32x4 __attribute__((ext_vector_type(4)));

__device__ __forceinline__ void threefry2x32(unsigned x0, unsigned x1,
                                             unsigned& o0, unsigned& o1) {
  const unsigned k0 = 0u, k1 = 42u;
  const unsigned k2 = 0x1BD11BDAu ^ k0 ^ k1;
  x0 += k0; x1 += k1;
#define TF_ROT(r) { x0 += x1; x1 = (x1 << (r)) | (x1 >> (32 - (r))); x1 ^= x0; }
  TF_ROT(13) TF_ROT(15) TF_ROT(26) TF_ROT(6)
  x0 += k1; x1 += k2 + 1u;
  TF_ROT(17) TF_ROT(29) TF_ROT(16) TF_ROT(24)
  x0 += k2; x1 += k0 + 2u;
  TF_ROT(13) TF_ROT(15) TF_ROT(26) TF_ROT(6)
  x0 += k0; x1 += k1 + 3u;
  TF_ROT(17) TF_ROT(29) TF_ROT(16) TF_ROT(24)
  x0 += k1; x1 += k2 + 4u;
  TF_ROT(13) TF_ROT(15) TF_ROT(26) TF_ROT(6)
  x0 += k2; x1 += k0 + 5u;
#undef TF_ROT
  o0 = x0; o1 = x1;
}

__device__ __forceinline__ void pack4h(_Float16* dstp, float4 v) {
  union { _Float16 h[4]; uint2 u; } p;
  p.h[0] = (_Float16)v.x; p.h[1] = (_Float16)v.y;
  p.h[2] = (_Float16)v.z; p.h[3] = (_Float16)v.w;
  *reinterpret_cast<uint2*>(dstp) = p.u;
}

// ass = softmax(logmap0(x) @ Wa^T), fp16 output. 64-row blocks, MFMA.
__global__ __launch_bounds__(256) void gemm_ass_kernel(
    const float* __restrict__ X, const float* __restrict__ W,
    __half* __restrict__ out, int N) {
  __shared__ __align__(16) char lbuf[64 * XP * 2 + 128 * XP * 2];
  _Float16* xh = (_Float16*)lbuf;                    // [64][XP]
  _Float16* wh = (_Float16*)(lbuf + 64 * XP * 2);    // [128][XP]
  float* scratch = (float*)(lbuf + 64 * XP * 2);     // [64][128], overlaps wh

  const int t = threadIdx.x;
  const int row0 = blockIdx.x * 64;

  // stage x fp32 -> scratch (linear)
#pragma unroll
  for (int i = 0; i < 8; ++i) {
    int f = t + 256 * i, r = f >> 5, c4 = f & 31;
    float4 v = make_float4(0.f, 0.f, 0.f, 0.f);
    if (row0 + r < N)
      v = *reinterpret_cast<const float4*>(X + (size_t)(row0 + r) * D128 + c4 * 4);
    *reinterpret_cast<float4*>(&scratch[r * 128 + c4 * 4]) = v;
  }
  __syncthreads();

  // logmap0 in place: row -> [0, d * narrow / ||narrow||]
#pragma unroll
  for (int rr = 0; rr < 2; ++rr) {
    int r = (t >> 3) + 32 * rr, tr = t & 7;
    float ss = 0.f;
    float4 ch[4];
#pragma unroll
    for (int i = 0; i < 4; ++i) {
      ch[i] = *reinterpret_cast<float4*>(&scratch[r * 128 + (tr + 8 * i) * 4]);
      ss += ch[i].x * ch[i].x + ch[i].y * ch[i].y + ch[i].z * ch[i].z + ch[i].w * ch[i].w;
    }
    if (tr == 0) ss -= ch[0].x * ch[0].x;
#pragma unroll
    for (int msk = 1; msk < 8; msk <<= 1) ss += __shfl_xor(ss, msk);
    float x0v = __shfl(ch[0].x, (t & 63) & ~7);
    float dd = acoshf(fmaxf(x0v, 1.f + 1e-6f));
    float sc = dd / fmaxf(sqrtf(ss), 1e-8f);
#pragma unroll
    for (int i = 0; i < 4; ++i) {
      float4 v = ch[i];
      v.x *= sc; v.y *= sc; v.z *= sc; v.w *= sc;
      if (tr == 0 && i == 0) v.x = 0.f;
      *reinterpret_cast<float4*>(&scratch[r * 128 + (tr + 8 * i) * 4]) = v;
    }
  }
  __syncthreads();

  // convert scratch -> xh fp16 (padded rows)
#pragma unroll
  for (int i = 0; i < 8; ++i) {
    int f = t + 256 * i, r = f >> 5, c4 = f & 31;
    float4 v = *reinterpret_cast<float4*>(&scratch[r * 128 + c4 * 4]);
    pack4h(&xh[r * XP + c4 * 4], v);
  }
  __syncthreads();

  // stage W -> wh fp16 (overwrites scratch region)
#pragma unroll
  for (int i = 0; i < 16; ++i) {
    int f = t + 256 * i, wr = f >> 5, c4 = f & 31;
    float4 v = *reinterpret_cast<const float4*>(W + (size_t)wr * D128 + c4 * 4);
    pack4h(&wh[wr * XP + c4 * 4], v);
  }
  __syncthreads();

  // MFMA: 4 waves x (16 rows x 128 cols)
  const int w = t >> 6, lane = t & 63;
  const int lc = lane & 15;
  const int arow = 16 * w + lc;
  const int koff = (lane >> 4) * 8;
  f32x4 acc[8];
#pragma unroll
  for (int i = 0; i < 8; ++i) acc[i] = (f32x4){0.f, 0.f, 0.f, 0.f};

#pragma unroll
  for (int kk = 0; kk < 4; ++kk) {
    f16x8 a = *reinterpret_cast<f16x8*>(&xh[arow * XP + kk * 32 + koff]);
#pragma unroll
    for (int tt = 0; tt < 8; ++tt) {
      f16x8 b = *reinterpret_cast<f16x8*>(&wh[(tt * 16 + lc) * XP + kk * 32 + koff]);
      acc[tt] = __builtin_amdgcn_mfma_f32_16x16x32_f16(a, b, acc[tt], 0, 0, 0);
    }
  }

  // epilogue: row softmax, fp16 out. D row = (lane>>4)*4+j, col = 16tt+lc.
#pragma unroll
  for (int j = 0; j < 4; ++j) {
    int gr = row0 + 16 * w + ((lane >> 4) << 2) + j;
    float mx = acc[0][j];
#pragma unroll
    for (int tt = 1; tt < 8; ++tt) mx = fmaxf(mx, acc[tt][j]);
#pragma unroll
    for (int msk = 1; msk < 16; msk <<= 1) mx = fmaxf(mx, __shfl_xor(mx, msk));
    float e[8], sm = 0.f;
#pragma unroll
    for (int tt = 0; tt < 8; ++tt) { e[tt] = expf(acc[tt][j] - mx); sm += e[tt]; }
#pragma unroll
    for (int msk = 1; msk < 16; msk <<= 1) sm += __shfl_xor(sm, msk);
    float inv = 1.f / sm;
    if (gr < N) {
#pragma unroll
      for (int tt = 0; tt < 8; ++tt)
        out[(size_t)gr * D128 + tt * 16 + lc] = __float2half(e[tt] * inv);
    }
  }
}

// q = lorentz(x@Wq^T) fp32, k = lorentz(x@Wk^T) fp16 — one X staging.
__global__ __launch_bounds__(256) void gemm_qk_kernel(
    const float* __restrict__ X, const float* __restrict__ Wq,
    const float* __restrict__ Wk, const float* __restrict__ lsq,
    const float* __restrict__ lsk, float* __restrict__ qout,
    __half* __restrict__ kout, int N) {
  __shared__ __align__(16) char lbuf[64 * XP * 2 + 128 * XP * 2];
  _Float16* xh = (_Float16*)lbuf;
  _Float16* wh = (_Float16*)(lbuf + 64 * XP * 2);

  const int t = threadIdx.x;
  const int row0 = blockIdx.x * 64;

  // stage x -> fp16 directly
#pragma unroll
  for (int i = 0; i < 8; ++i) {
    int f = t + 256 * i, r = f >> 5, c4 = f & 31;
    float4 v = make_float4(0.f, 0.f, 0.f, 0.f);
    if (row0 + r < N)
      v = *reinterpret_cast<const float4*>(X + (size_t)(row0 + r) * D128 + c4 * 4);
    pack4h(&xh[r * XP + c4 * 4], v);
  }

  const int w = t >> 6, lane = t & 63;
  const int lc = lane & 15;
  const int arow = 16 * w + lc;
  const int koff = (lane >> 4) * 8;

  for (int pass = 0; pass < 2; ++pass) {
    const float* W = pass ? Wk : Wq;
    if (pass) __syncthreads();   // all waves done reading wh from pass 0
#pragma unroll
    for (int i = 0; i < 16; ++i) {
      int f = t + 256 * i, wr = f >> 5, c4 = f & 31;
      float4 v = *reinterpret_cast<const float4*>(W + (size_t)wr * D128 + c4 * 4);
      pack4h(&wh[wr * XP + c4 * 4], v);
    }
    __syncthreads();

    f32x4 acc[8];
#pragma unroll
    for (int i = 0; i < 8; ++i) acc[i] = (f32x4){0.f, 0.f, 0.f, 0.f};
#pragma unroll
    for (int kk = 0; kk < 4; ++kk) {
      f16x8 a = *reinterpret_cast<f16x8*>(&xh[arow * XP + kk * 32 + koff]);
#pragma unroll
      for (int tt = 0; tt < 8; ++tt) {
        f16x8 b = *reinterpret_cast<f16x8*>(&wh[(tt * 16 + lc) * XP + kk * 32 + koff]);
        acc[tt] = __builtin_amdgcn_mfma_f32_16x16x32_f16(a, b, acc[tt], 0, 0, 0);
      }
    }

    float scale = expf(pass ? lsk[0] : lsq[0]);
#pragma unroll
    for (int j = 0; j < 4; ++j) {
      int gr = row0 + 16 * w + ((lane >> 4) << 2) + j;
      float ss = 0.f;
#pragma unroll
      for (int tt = 0; tt < 8; ++tt) {
        float v = acc[tt][j];
        if (tt == 0 && lc == 0) v = 0.f;   // narrow excludes col 0
        ss += v * v;
      }
#pragma unroll
      for (int msk = 1; msk < 16; msk <<= 1) ss += __shfl_xor(ss, msk);
      float y0 = __shfl(acc[0][j], lane & ~15);
      float tm = scale / (1.f + expf(-y0)) + 1.1f;
      float qs = sqrtf((tm * tm - 1.f) / fmaxf(ss, 1e-8f));
      if (gr < N) {
        if (pass == 0) {
#pragma unroll
          for (int tt = 0; tt < 8; ++tt) {
            float val = acc[tt][j] * qs;
            if (tt == 0 && lc == 0) val = tm;
            qout[(size_t)gr * D128 + tt * 16 + lc] = val;
          }
        } else {
#pragma unroll
          for (int tt = 0; tt < 8; ++tt) {
            float val = acc[tt][j] * qs;
            if (tt == 0 && lc == 0) val = tm;
            kout[(size_t)gr * D128 + tt * 16 + lc] = __float2half(val);
          }
        }
      }
    }
  }
}

// counts[src[e]]++
__global__ __launch_bounds__(256) void count_kernel(const int* __restrict__ src,
                                                    int* __restrict__ counts, int E) {
  int e = blockIdx.x * 256 + threadIdx.x;
  if (e < E) atomicAdd(&counts[src[e]], 1);
}

// --- 3-kernel exclusive scan of counts -> start, cursor ---
__global__ __launch_bounds__(256) void scan1_kernel(const int* __restrict__ counts,
                                                    int* __restrict__ incl,
                                                    int* __restrict__ partials, int N) {
  int i = blockIdx.x * 256 + threadIdx.x;
  int c = (i < N) ? counts[i] : 0;
  int lane = threadIdx.x & 63, w = threadIdx.x >> 6;
  int v = c;
#pragma unroll
  for (int d = 1; d < 64; d <<= 1) {
    int tv = __shfl_up(v, d);
    if (lane >= d) v += tv;
  }
  __shared__ int wsum[4];
  if (lane == 63) wsum[w] = v;
  __syncthreads();
  int add = 0;
  for (int j = 0; j < w; ++j) add += wsum[j];
  v += add;
  if (i < N) incl[i] = v;
  if (threadIdx.x == 255) partials[blockIdx.x] = v;
}

__global__ __launch_bounds__(256) void scan2_kernel(int* __restrict__ partials, int nparts) {
  int t = threadIdx.x;
  int p = (t < nparts) ? partials[t] : 0;
  int lane = t & 63, w = t >> 6;
  int v = p;
#pragma unroll
  for (int d = 1; d < 64; d <<= 1) {
    int tv = __shfl_up(v, d);
    if (lane >= d) v += tv;
  }
  __shared__ int wsum[4];
  if (lane == 63) wsum[w] = v;
  __syncthreads();
  int add = 0;
  for (int j = 0; j < w; ++j) add += wsum[j];
  v += add;
  if (t < nparts) partials[t] = v - p;
}

__global__ __launch_bounds__(256) void scan3_kernel(const int* __restrict__ counts,
                                                    int* __restrict__ incl_to_start,
                                                    int* __restrict__ cursor,
                                                    const int* __restrict__ partials, int N) {
  int i = blockIdx.x * 256 + threadIdx.x;
  if (i < N) {
    int s = incl_to_start[i] - counts[i] + partials[blockIdx.x];
    incl_to_start[i] = s;
    cursor[i] = s;
  }
}

// scatter dst into CSR (segment-sorted) order
__global__ __launch_bounds__(256) void csr_fill_kernel(
    const int* __restrict__ src, const int* __restrict__ dst,
    int* __restrict__ cursor, int* __restrict__ dst_s, int E) {
  int e = blockIdx.x * 256 + threadIdx.x;
  if (e < E) {
    int pos = atomicAdd(&cursor[src[e]], 1);
    dst_s[pos] = dst[e];
  }
}

// One 16-lane group per node; closed-form softmax weight; fp16 k/ass gathers.
__global__ __launch_bounds__(256) void node_fused_kernel(
    const float* __restrict__ q, const __half* __restrict__ kh,
    const __half* __restrict__ ass, const int* __restrict__ start,
    const int* __restrict__ counts, const int* __restrict__ dst_s,
    float* __restrict__ out, int N) {
  int g = threadIdx.x >> 4;
  int lq = threadIdx.x & 15;
  int n = blockIdx.x * 16 + g;
  if (n >= N) return;
  int st = start[n], deg = counts[n];
  int c8 = lq * 8;

  float4 qa = *reinterpret_cast<const float4*>(q + (size_t)n * D128 + c8);
  float4 qb = *reinterpret_cast<const float4*>(q + (size_t)n * D128 + c8 + 4);

  float lsum = 0.f;
  float acc[8];
#pragma unroll
  for (int j = 0; j < 8; ++j) acc[j] = 0.f;

  if (deg > 0) {
    int d_cur = dst_s[st];
    int d_nxt = (deg > 1) ? dst_s[st + 1] : d_cur;
    uint4 kv = *reinterpret_cast<const uint4*>(kh + (size_t)d_cur * D128 + c8);
    uint4 av = *reinterpret_cast<const uint4*>(ass + (size_t)d_cur * D128 + c8);

    for (int i = 0; i < deg; ++i) {
      uint4 kv_n = *reinterpret_cast<const uint4*>(kh + (size_t)d_nxt * D128 + c8);
      uint4 av_n = *reinterpret_cast<const uint4*>(ass + (size_t)d_nxt * D128 + c8);
      int p2 = st + i + 2;
      int d_nn = dst_s[(p2 < st + deg) ? p2 : st];

      const __half2* kp = reinterpret_cast<const __half2*>(&kv);
      float2 k0 = __half22float2(kp[0]);
      float2 k1 = __half22float2(kp[1]);
      float2 k2 = __half22float2(kp[2]);
      float2 k3 = __half22float2(kp[3]);
      float part = qa.x * k0.x + qa.y * k0.y + qa.z * k1.x + qa.w * k1.y +
                   qb.x * k2.x + qb.y * k2.y + qb.z * k3.x + qb.w * k3.y;
      part = (lq == 0) ? (2.f * qa.x * k0.x - part) : (-part);
#pragma unroll
      for (int msk = 1; msk < 16; msk <<= 1) part += __shfl_xor(part, msk);

      // w = exp(-acosh(x)) = 1/(x + sqrt(x^2-1)), x clipped to 1+1e-6
      float x = fmaxf(part, 1.f + 1e-6f);
      float tt = x + sqrtf(__builtin_fmaf(x, x, -1.f));
      float w = __builtin_amdgcn_rcpf(tt);

      lsum += w;
      const __half2* hp = reinterpret_cast<const __half2*>(&av);
      float2 v0 = __half22float2(hp[0]);
      float2 v1 = __half22float2(hp[1]);
      float2 v2 = __half22float2(hp[2]);
      float2 v3 = __half22float2(hp[3]);
      acc[0] += w * v0.x;  acc[1] += w * v0.y;
      acc[2] += w * v1.x;  acc[3] += w * v1.y;
      acc[4] += w * v2.x;  acc[5] += w * v2.y;
      acc[6] += w * v3.x;  acc[7] += w * v3.y;

      kv = kv_n; av = av_n;
      d_nxt = d_nn;
    }
  }

  float inv = (deg > 0) ? 1.f / fmaxf(lsum, 1e-8f) : 0.f;

  float vg[8];
#pragma unroll
  for (int j = 0; j < 8; ++j) {
    unsigned o0, o1;
    threefry2x32(0u, (unsigned)(n * D128 + c8 + j), o0, o1);
    unsigned bits = o0 ^ o1;
    float f = __uint_as_float((bits >> 9) | 0x3f800000u) - 1.0f;
    float u = fmaxf(1e-10f, f * (1.0f - 1e-10f) + 1e-10f);
    float gmb = -logf(-logf(u));
    vg[j] = (logf(acc[j] * inv + 1e-6f) + gmb) / 0.2f;
  }
  float mm = vg[0];
#pragma unroll
  for (int j = 1; j < 8; ++j) mm = fmaxf(mm, vg[j]);
#pragma unroll
  for (int msk = 1; msk < 16; msk <<= 1) mm = fmaxf(mm, __shfl_xor(mm, msk));
  float sm = 0.f;
#pragma unroll
  for (int j = 0; j < 8; ++j) { vg[j] = expf(vg[j] - mm); sm += vg[j]; }
#pragma unroll
  for (int msk = 1; msk < 16; msk <<= 1) sm += __shfl_xor(sm, msk);
  float invs = 1.f / sm;
  *reinterpret_cast<float4*>(out + (size_t)n * D128 + c8) =
      make_float4(vg[0] * invs, vg[1] * invs, vg[2] * invs, vg[3] * invs);
  *reinterpret_cast<float4*>(out + (size_t)n * D128 + c8 + 4) =
      make_float4(vg[4] * invs, vg[5] * invs, vg[6] * invs, vg[7] * invs);
}

extern "C" void kernel_launch(void* const* d_in, const int* in_sizes, int n_in,
                              void* d_out, int out_size, void* d_ws, size_t ws_size,
                              hipStream_t stream) {
  const float* x   = (const float*)d_in[0];
  const int*   src = (const int*)d_in[1];
  const int*   dst = (const int*)d_in[2];
  // d_in[3] = edge_value (unused by reference)
  const float* Wq  = (const float*)d_in[4];
  const float* Wk  = (const float*)d_in[5];
  const float* Wa  = (const float*)d_in[6];
  const float* lsq = (const float*)d_in[7];
  const float* lsk = (const float*)d_in[8];
  const int N = in_sizes[0] / D128;
  const int E = in_sizes[1];
  float* out = (float*)d_out;

  float*  qbuf    = (float*)d_ws;
  __half* kbuf    = (__half*)(qbuf + (size_t)N * D128);
  __half* abuf    = kbuf + (size_t)N * D128;
  int*    counts  = (int*)(abuf + (size_t)N * D128);
  int*    startv  = counts + N;
  int*    cursor  = startv + N;
  int*    partials= cursor + N;
  int*    dst_s   = partials + 256;

  hipMemsetAsync(counts, 0, (size_t)N * sizeof(int), stream);

  const int gemm_blocks = (N + 63) / 64;
  gemm_ass_kernel<<<gemm_blocks, 256, 0, stream>>>(x, Wa, abuf, N);
  gemm_qk_kernel<<<gemm_blocks, 256, 0, stream>>>(x, Wq, Wk, lsq, lsk, qbuf, kbuf, N);

  const int eb = (E + 255) / 256;
  count_kernel<<<eb, 256, 0, stream>>>(src, counts, E);

  const int nb = (N + 255) / 256;
  scan1_kernel<<<nb, 256, 0, stream>>>(counts, startv, partials, N);
  scan2_kernel<<<1, 256, 0, stream>>>(partials, nb);
  scan3_kernel<<<nb, 256, 0, stream>>>(counts, startv, cursor, partials, N);
  csr_fill_kernel<<<eb, 256, 0, stream>>>(src, dst, cursor, dst_s, E);

  node_fused_kernel<<<(N + 15) / 16, 256, 0, stream>>>(qbuf, kbuf, abuf, startv,
                                                       counts, dst_s, out, N);
}

// Round 11
// 212.988 us; speedup vs baseline: 4.4207x; 1.0566x over previous
//
#include <hip/hip_runtime.h>
#include <hip/hip_bf16.h>
#include <hip/hip_fp16.h>
#include <math.h>

// ---------------------------------------------------------------------------
// LorentzAssignment on MI355X.
//   0. cvt: x, Wq, Wk, Wa -> fp16 once (workspace).
//   1. gemm_ass: logmap0(x) @ Wa^T via fp16 MFMA, softmax, fp16 out.
//   2. gemm_qk : x @ Wq^T / x @ Wk^T from one X staging; lorentz tail;
//                q stored fp16 with NEGATED narrow part ([t, -s*narrow]) so
//                the Lorentz inner product is a plain dot; k stored fp16.
//   3. CSR build (count -> scan -> scatter dst_s).
//   4. node_fused: per-node closed-form softmax w = 1/(x+sqrt(x^2-1)),
//      v_dot2_f32_f16 dot, fp32 accumulate, fused gumbel-softmax.
// ---------------------------------------------------------------------------

#define D128 128
#define XP 136                    // padded fp16 row length (272B, %16==0)

typedef _Float16 f16x2 __attribute__((ext_vector_type(2)));
typedef _Float16 f16x8 __attribute__((ext_vector_type(8)));
typedef float f32x4 __attribute__((ext_vector_type(4)));

union U4 { uint4 u; f16x2 f2[4]; __half2 hh[4]; };

__device__ __forceinline__ void threefry2x32(unsigned x0, unsigned x1,
                                             unsigned& o0, unsigned& o1) {
  const unsigned k0 = 0u, k1 = 42u;
  const unsigned k2 = 0x1BD11BDAu ^ k0 ^ k1;
  x0 += k0; x1 += k1;
#define TF_ROT(r) { x0 += x1; x1 = (x1 << (r)) | (x1 >> (32 - (r))); x1 ^= x0; }
  TF_ROT(13) TF_ROT(15) TF_ROT(26) TF_ROT(6)
  x0 += k1; x1 += k2 + 1u;
  TF_ROT(17) TF_ROT(29) TF_ROT(16) TF_ROT(24)
  x0 += k2; x1 += k0 + 2u;
  TF_ROT(13) TF_ROT(15) TF_ROT(26) TF_ROT(6)
  x0 += k0; x1 += k1 + 3u;
  TF_ROT(17) TF_ROT(29) TF_ROT(16) TF_ROT(24)
  x0 += k1; x1 += k2 + 4u;
  TF_ROT(13) TF_ROT(15) TF_ROT(26) TF_ROT(6)
  x0 += k2; x1 += k0 + 5u;
#undef TF_ROT
  o0 = x0; o1 = x1;
}

// fp32 -> fp16 bulk convert: x (nx8 chunks of 8) then Wq/Wk/Wa (2048 each).
__global__ __launch_bounds__(256) void cvt_kernel(
    const float* __restrict__ x, const float* __restrict__ Wq,
    const float* __restrict__ Wk, const float* __restrict__ Wa,
    __half* __restrict__ xh, __half* __restrict__ wqh,
    __half* __restrict__ wkh, __half* __restrict__ wah, int nx8) {
  int i = blockIdx.x * 256 + threadIdx.x;
  const float* src; __half* dst; size_t off;
  if (i < nx8) {
    src = x; dst = xh; off = (size_t)i * 8;
  } else {
    int j = i - nx8; int w = j >> 11; int r = j & 2047;
    if (w >= 3) return;
    off = (size_t)r * 8;
    src = (w == 0) ? Wq : (w == 1) ? Wk : Wa;
    dst = (w == 0) ? wqh : (w == 1) ? wkh : wah;
  }
  float4 a = *reinterpret_cast<const float4*>(src + off);
  float4 b = *reinterpret_cast<const float4*>(src + off + 4);
  union { __half2 h2[4]; uint4 u; } pk;
  pk.h2[0] = __floats2half2_rn(a.x, a.y);
  pk.h2[1] = __floats2half2_rn(a.z, a.w);
  pk.h2[2] = __floats2half2_rn(b.x, b.y);
  pk.h2[3] = __floats2half2_rn(b.z, b.w);
  *reinterpret_cast<uint4*>(dst + off) = pk.u;
}

// ass = softmax(logmap0(x) @ Wa^T), fp16 in/out, MFMA.
__global__ __launch_bounds__(256) void gemm_ass_kernel(
    const __half* __restrict__ xh_g, const __half* __restrict__ wh_g,
    __half* __restrict__ out, int N) {
  __shared__ __align__(16) _Float16 xs[64 * XP];
  __shared__ __align__(16) _Float16 wh[128 * XP];

  const int t = threadIdx.x;
  const int row0 = blockIdx.x * 64;

  // logmap0 while staging x into LDS (fp16 -> fp32 -> fp16)
#pragma unroll
  for (int rr = 0; rr < 2; ++rr) {
    int r = (t >> 3) + 32 * rr, tr = t & 7;
    int gr = row0 + r;
    U4 c0, c1;
    c0.u = make_uint4(0, 0, 0, 0); c1.u = make_uint4(0, 0, 0, 0);
    if (gr < N) {
      c0.u = *reinterpret_cast<const uint4*>(xh_g + (size_t)gr * D128 + tr * 16);
      c1.u = *reinterpret_cast<const uint4*>(xh_g + (size_t)gr * D128 + tr * 16 + 8);
    }
    float v[16];
    float ss = 0.f;
#pragma unroll
    for (int j = 0; j < 4; ++j) {
      float2 f = __half22float2(c0.hh[j]);
      v[2 * j] = f.x; v[2 * j + 1] = f.y; ss += f.x * f.x + f.y * f.y;
    }
#pragma unroll
    for (int j = 0; j < 4; ++j) {
      float2 f = __half22float2(c1.hh[j]);
      v[8 + 2 * j] = f.x; v[9 + 2 * j] = f.y; ss += f.x * f.x + f.y * f.y;
    }
    if (tr == 0) ss -= v[0] * v[0];
#pragma unroll
    for (int msk = 1; msk < 8; msk <<= 1) ss += __shfl_xor(ss, msk);
    float x0v = __shfl(v[0], (t & 63) & ~7);
    float dd = acoshf(fmaxf(x0v, 1.f + 1e-6f));
    float sc = dd / fmaxf(sqrtf(ss), 1e-8f);
#pragma unroll
    for (int j = 0; j < 16; ++j) v[j] *= sc;
    if (tr == 0) v[0] = 0.f;
    union { __half2 h2[4]; uint4 u; } pk;
#pragma unroll
    for (int j = 0; j < 4; ++j) pk.h2[j] = __floats2half2_rn(v[2 * j], v[2 * j + 1]);
    *reinterpret_cast<uint4*>(&xs[r * XP + tr * 16]) = pk.u;
#pragma unroll
    for (int j = 0; j < 4; ++j) pk.h2[j] = __floats2half2_rn(v[8 + 2 * j], v[9 + 2 * j]);
    *reinterpret_cast<uint4*>(&xs[r * XP + tr * 16 + 8]) = pk.u;
  }

  // stage W fp16 (32KB, 8 iters)
#pragma unroll
  for (int i = 0; i < 8; ++i) {
    int f = t + 256 * i, wr = f >> 4, c8 = f & 15;
    *reinterpret_cast<uint4*>(&wh[wr * XP + c8 * 8]) =
        *reinterpret_cast<const uint4*>(wh_g + (size_t)wr * D128 + c8 * 8);
  }
  __syncthreads();

  const int w = t >> 6, lane = t & 63;
  const int lc = lane & 15;
  const int arow = 16 * w + lc;
  const int koff = (lane >> 4) * 8;
  f32x4 acc[8];
#pragma unroll
  for (int i = 0; i < 8; ++i) acc[i] = (f32x4){0.f, 0.f, 0.f, 0.f};

#pragma unroll
  for (int kk = 0; kk < 4; ++kk) {
    f16x8 a = *reinterpret_cast<f16x8*>(&xs[arow * XP + kk * 32 + koff]);
#pragma unroll
    for (int tt = 0; tt < 8; ++tt) {
      f16x8 b = *reinterpret_cast<f16x8*>(&wh[(tt * 16 + lc) * XP + kk * 32 + koff]);
      acc[tt] = __builtin_amdgcn_mfma_f32_16x16x32_f16(a, b, acc[tt], 0, 0, 0);
    }
  }

  // row softmax epilogue, fp16 out. D row = (lane>>4)*4+j, col = 16tt+lc.
#pragma unroll
  for (int j = 0; j < 4; ++j) {
    int gr = row0 + 16 * w + ((lane >> 4) << 2) + j;
    float mx = acc[0][j];
#pragma unroll
    for (int tt = 1; tt < 8; ++tt) mx = fmaxf(mx, acc[tt][j]);
#pragma unroll
    for (int msk = 1; msk < 16; msk <<= 1) mx = fmaxf(mx, __shfl_xor(mx, msk));
    float e[8], sm = 0.f;
#pragma unroll
    for (int tt = 0; tt < 8; ++tt) { e[tt] = expf(acc[tt][j] - mx); sm += e[tt]; }
#pragma unroll
    for (int msk = 1; msk < 16; msk <<= 1) sm += __shfl_xor(sm, msk);
    float inv = 1.f / sm;
    if (gr < N) {
#pragma unroll
      for (int tt = 0; tt < 8; ++tt)
        out[(size_t)gr * D128 + tt * 16 + lc] = __float2half(e[tt] * inv);
    }
  }
}

// q = lorentz(x@Wq^T) fp16 NEGATED-narrow, k = lorentz(x@Wk^T) fp16.
__global__ __launch_bounds__(256) void gemm_qk_kernel(
    const __half* __restrict__ xh_g, const __half* __restrict__ wqh_g,
    const __half* __restrict__ wkh_g, const float* __restrict__ lsq,
    const float* __restrict__ lsk, __half* __restrict__ qout,
    __half* __restrict__ kout, int N) {
  __shared__ __align__(16) _Float16 xs[64 * XP];
  __shared__ __align__(16) _Float16 wh[128 * XP];

  const int t = threadIdx.x;
  const int row0 = blockIdx.x * 64;

  // stage X tile fp16 (4 iters)
#pragma unroll
  for (int i = 0; i < 4; ++i) {
    int f = t + 256 * i, r = f >> 4, c8 = f & 15;
    uint4 v = make_uint4(0, 0, 0, 0);
    if (row0 + r < N)
      v = *reinterpret_cast<const uint4*>(xh_g + (size_t)(row0 + r) * D128 + c8 * 8);
    *reinterpret_cast<uint4*>(&xs[r * XP + c8 * 8]) = v;
  }

  const int w = t >> 6, lane = t & 63;
  const int lc = lane & 15;
  const int arow = 16 * w + lc;
  const int koff = (lane >> 4) * 8;

  for (int p = 0; p < 2; ++p) {
    const __half* Wg = p ? wkh_g : wqh_g;
    if (p) __syncthreads();
#pragma unroll
    for (int i = 0; i < 8; ++i) {
      int f = t + 256 * i, wr = f >> 4, c8 = f & 15;
      *reinterpret_cast<uint4*>(&wh[wr * XP + c8 * 8]) =
          *reinterpret_cast<const uint4*>(Wg + (size_t)wr * D128 + c8 * 8);
    }
    __syncthreads();

    f32x4 acc[8];
#pragma unroll
    for (int i = 0; i < 8; ++i) acc[i] = (f32x4){0.f, 0.f, 0.f, 0.f};
#pragma unroll
    for (int kk = 0; kk < 4; ++kk) {
      f16x8 a = *reinterpret_cast<f16x8*>(&xs[arow * XP + kk * 32 + koff]);
#pragma unroll
      for (int tt = 0; tt < 8; ++tt) {
        f16x8 b = *reinterpret_cast<f16x8*>(&wh[(tt * 16 + lc) * XP + kk * 32 + koff]);
        acc[tt] = __builtin_amdgcn_mfma_f32_16x16x32_f16(a, b, acc[tt], 0, 0, 0);
      }
    }

    float scale = expf(p ? lsk[0] : lsq[0]);
    __half* outp = p ? kout : qout;
    float sgn = p ? 1.f : -1.f;
#pragma unroll
    for (int j = 0; j < 4; ++j) {
      int gr = row0 + 16 * w + ((lane >> 4) << 2) + j;
      float ss = 0.f;
#pragma unroll
      for (int tt = 0; tt < 8; ++tt) {
        float v = acc[tt][j];
        if (tt == 0 && lc == 0) v = 0.f;
        ss += v * v;
      }
#pragma unroll
      for (int msk = 1; msk < 16; msk <<= 1) ss += __shfl_xor(ss, msk);
      float y0 = __shfl(acc[0][j], lane & ~15);
      float tm = scale / (1.f + expf(-y0)) + 1.1f;
      float qs = sqrtf((tm * tm - 1.f) / fmaxf(ss, 1e-8f)) * sgn;
      if (gr < N) {
#pragma unroll
        for (int tt = 0; tt < 8; ++tt) {
          float val = acc[tt][j] * qs;
          if (tt == 0 && lc == 0) val = tm;
          outp[(size_t)gr * D128 + tt * 16 + lc] = __float2half(val);
        }
      }
    }
  }
}

// counts[src[e]]++
__global__ __launch_bounds__(256) void count_kernel(const int* __restrict__ src,
                                                    int* __restrict__ counts, int E) {
  int e = blockIdx.x * 256 + threadIdx.x;
  if (e < E) atomicAdd(&counts[src[e]], 1);
}

// --- 3-kernel exclusive scan of counts -> start, cursor ---
__global__ __launch_bounds__(256) void scan1_kernel(const int* __restrict__ counts,
                                                    int* __restrict__ incl,
                                                    int* __restrict__ partials, int N) {
  int i = blockIdx.x * 256 + threadIdx.x;
  int c = (i < N) ? counts[i] : 0;
  int lane = threadIdx.x & 63, w = threadIdx.x >> 6;
  int v = c;
#pragma unroll
  for (int d = 1; d < 64; d <<= 1) {
    int tv = __shfl_up(v, d);
    if (lane >= d) v += tv;
  }
  __shared__ int wsum[4];
  if (lane == 63) wsum[w] = v;
  __syncthreads();
  int add = 0;
  for (int j = 0; j < w; ++j) add += wsum[j];
  v += add;
  if (i < N) incl[i] = v;
  if (threadIdx.x == 255) partials[blockIdx.x] = v;
}

__global__ __launch_bounds__(256) void scan2_kernel(int* __restrict__ partials, int nparts) {
  int t = threadIdx.x;
  int p = (t < nparts) ? partials[t] : 0;
  int lane = t & 63, w = t >> 6;
  int v = p;
#pragma unroll
  for (int d = 1; d < 64; d <<= 1) {
    int tv = __shfl_up(v, d);
    if (lane >= d) v += tv;
  }
  __shared__ int wsum[4];
  if (lane == 63) wsum[w] = v;
  __syncthreads();
  int add = 0;
  for (int j = 0; j < w; ++j) add += wsum[j];
  v += add;
  if (t < nparts) partials[t] = v - p;
}

__global__ __launch_bounds__(256) void scan3_kernel(const int* __restrict__ counts,
                                                    int* __restrict__ incl_to_start,
                                                    int* __restrict__ cursor,
                                                    const int* __restrict__ partials, int N) {
  int i = blockIdx.x * 256 + threadIdx.x;
  if (i < N) {
    int s = incl_to_start[i] - counts[i] + partials[blockIdx.x];
    incl_to_start[i] = s;
    cursor[i] = s;
  }
}

// scatter dst into CSR (segment-sorted) order
__global__ __launch_bounds__(256) void csr_fill_kernel(
    const int* __restrict__ src, const int* __restrict__ dst,
    int* __restrict__ cursor, int* __restrict__ dst_s, int E) {
  int e = blockIdx.x * 256 + threadIdx.x;
  if (e < E) {
    int pos = atomicAdd(&cursor[src[e]], 1);
    dst_s[pos] = dst[e];
  }
}

// One 16-lane group per node; plain dot (q narrow pre-negated) via fdot2;
// closed-form softmax weight; fp32 accumulate; fused gumbel-softmax.
__global__ __launch_bounds__(256) void node_fused_kernel(
    const __half* __restrict__ qh, const __half* __restrict__ kh,
    const __half* __restrict__ ass, const int* __restrict__ start,
    const int* __restrict__ counts, const int* __restrict__ dst_s,
    float* __restrict__ out, int N) {
  int g = threadIdx.x >> 4;
  int lq = threadIdx.x & 15;
  int n = blockIdx.x * 16 + g;
  if (n >= N) return;
  int st = start[n], deg = counts[n];
  int c8 = lq * 8;

  U4 qv;
  qv.u = *reinterpret_cast<const uint4*>(qh + (size_t)n * D128 + c8);

  float lsum = 0.f;
  float acc[8];
#pragma unroll
  for (int j = 0; j < 8; ++j) acc[j] = 0.f;

  if (deg > 0) {
    int d_cur = dst_s[st];
    int d_nxt = (deg > 1) ? dst_s[st + 1] : d_cur;
    U4 kv, av;
    kv.u = *reinterpret_cast<const uint4*>(kh + (size_t)d_cur * D128 + c8);
    av.u = *reinterpret_cast<const uint4*>(ass + (size_t)d_cur * D128 + c8);

    for (int i = 0; i < deg; ++i) {
      U4 kvn, avn;
      kvn.u = *reinterpret_cast<const uint4*>(kh + (size_t)d_nxt * D128 + c8);
      avn.u = *reinterpret_cast<const uint4*>(ass + (size_t)d_nxt * D128 + c8);
      int p2 = st + i + 2;
      int d_nn = dst_s[(p2 < st + deg) ? p2 : st];

      float part = __builtin_amdgcn_fdot2(qv.f2[0], kv.f2[0],
                   __builtin_amdgcn_fdot2(qv.f2[1], kv.f2[1],
                   __builtin_amdgcn_fdot2(qv.f2[2], kv.f2[2],
                   __builtin_amdgcn_fdot2(qv.f2[3], kv.f2[3], 0.f, false),
                   false), false), false);
#pragma unroll
      for (int msk = 1; msk < 16; msk <<= 1) part += __shfl_xor(part, msk);

      // w = exp(-acosh(x)) = 1/(x + sqrt(x^2-1)), x clipped to 1+1e-6
      float x = fmaxf(part, 1.f + 1e-6f);
      float tt = x + sqrtf(__builtin_fmaf(x, x, -1.f));
      float w = __builtin_amdgcn_rcpf(tt);

      lsum += w;
      float2 v0 = __half22float2(av.hh[0]);
      float2 v1 = __half22float2(av.hh[1]);
      float2 v2 = __half22float2(av.hh[2]);
      float2 v3 = __half22float2(av.hh[3]);
      acc[0] += w * v0.x;  acc[1] += w * v0.y;
      acc[2] += w * v1.x;  acc[3] += w * v1.y;
      acc[4] += w * v2.x;  acc[5] += w * v2.y;
      acc[6] += w * v3.x;  acc[7] += w * v3.y;

      kv = kvn; av = avn;
      d_nxt = d_nn;
    }
  }

  float inv = (deg > 0) ? 1.f / fmaxf(lsum, 1e-8f) : 0.f;

  float vg[8];
#pragma unroll
  for (int j = 0; j < 8; ++j) {
    unsigned o0, o1;
    threefry2x32(0u, (unsigned)(n * D128 + c8 + j), o0, o1);
    unsigned bits = o0 ^ o1;
    float f = __uint_as_float((bits >> 9) | 0x3f800000u) - 1.0f;
    float u = fmaxf(1e-10f, f * (1.0f - 1e-10f) + 1e-10f);
    float gmb = -logf(-logf(u));
    vg[j] = (logf(acc[j] * inv + 1e-6f) + gmb) / 0.2f;
  }
  float mm = vg[0];
#pragma unroll
  for (int j = 1; j < 8; ++j) mm = fmaxf(mm, vg[j]);
#pragma unroll
  for (int msk = 1; msk < 16; msk <<= 1) mm = fmaxf(mm, __shfl_xor(mm, msk));
  float sm = 0.f;
#pragma unroll
  for (int j = 0; j < 8; ++j) { vg[j] = expf(vg[j] - mm); sm += vg[j]; }
#pragma unroll
  for (int msk = 1; msk < 16; msk <<= 1) sm += __shfl_xor(sm, msk);
  float invs = 1.f / sm;
  *reinterpret_cast<float4*>(out + (size_t)n * D128 + c8) =
      make_float4(vg[0] * invs, vg[1] * invs, vg[2] * invs, vg[3] * invs);
  *reinterpret_cast<float4*>(out + (size_t)n * D128 + c8 + 4) =
      make_float4(vg[4] * invs, vg[5] * invs, vg[6] * invs, vg[7] * invs);
}

extern "C" void kernel_launch(void* const* d_in, const int* in_sizes, int n_in,
                              void* d_out, int out_size, void* d_ws, size_t ws_size,
                              hipStream_t stream) {
  const float* x   = (const float*)d_in[0];
  const int*   src = (const int*)d_in[1];
  const int*   dst = (const int*)d_in[2];
  // d_in[3] = edge_value (unused by reference)
  const float* Wq  = (const float*)d_in[4];
  const float* Wk  = (const float*)d_in[5];
  const float* Wa  = (const float*)d_in[6];
  const float* lsq = (const float*)d_in[7];
  const float* lsk = (const float*)d_in[8];
  const int N = in_sizes[0] / D128;
  const int E = in_sizes[1];
  float* out = (float*)d_out;

  __half* xh   = (__half*)d_ws;
  __half* qh   = xh + (size_t)N * D128;
  __half* kh   = qh + (size_t)N * D128;
  __half* ah   = kh + (size_t)N * D128;
  __half* wqh  = ah + (size_t)N * D128;
  __half* wkh  = wqh + 16384;
  __half* wah  = wkh + 16384;
  int* counts  = (int*)(wah + 16384);
  int* startv  = counts + N;
  int* cursor  = startv + N;
  int* partials= cursor + N;
  int* dst_s   = partials + 256;

  hipMemsetAsync(counts, 0, (size_t)N * sizeof(int), stream);

  const int nx8 = N * 16;                       // N*128/8
  const int cvt_blocks = (nx8 + 3 * 2048 + 255) / 256;
  cvt_kernel<<<cvt_blocks, 256, 0, stream>>>(x, Wq, Wk, Wa, xh, wqh, wkh, wah, nx8);

  const int gemm_blocks = (N + 63) / 64;
  gemm_ass_kernel<<<gemm_blocks, 256, 0, stream>>>(xh, wah, ah, N);
  gemm_qk_kernel<<<gemm_blocks, 256, 0, stream>>>(xh, wqh, wkh, lsq, lsk, qh, kh, N);

  const int eb = (E + 255) / 256;
  count_kernel<<<eb, 256, 0, stream>>>(src, counts, E);

  const int nb = (N + 255) / 256;
  scan1_kernel<<<nb, 256, 0, stream>>>(counts, startv, partials, N);
  scan2_kernel<<<1, 256, 0, stream>>>(partials, nb);
  scan3_kernel<<<nb, 256, 0, stream>>>(counts, startv, cursor, partials, N);
  csr_fill_kernel<<<eb, 256, 0, stream>>>(src, dst, cursor, dst_s, E);

  node_fused_kernel<<<(N + 15) / 16, 256, 0, stream>>>(qh, kh, ah, startv,
                                                       counts, dst_s, out, N);
}

// Round 12
// 207.687 us; speedup vs baseline: 4.5336x; 1.0255x over previous
//
#include <hip/hip_runtime.h>
#include <hip/hip_bf16.h>
#include <hip/hip_fp16.h>
#include <math.h>

// ---------------------------------------------------------------------------
// LorentzAssignment on MI355X.
//   0. cvt_count: Wq/Wk/Wa -> fp16 (24 blocks) + per-src edge counts (rest).
//   1. gemm3: ONE kernel, one X staging (fp32->fp16 in LDS):
//        pass0: q = lorentz(x@Wq^T)  -> fp16, narrow NEGATED
//        pass1: k = lorentz(x@Wk^T)  -> fp16
//        logmap0 in-place on LDS tile
//        pass2: ass = softmax(logmap0(x)@Wa^T) -> fp16
//   2. CSR build (scan -> scatter dst_s).
//   3. node_fused: closed-form softmax w = 1/(x+sqrt(x^2-1)), fdot2 dots,
//      prefetch-2 pipeline on k/ass gathers, fused gumbel-softmax.
// ---------------------------------------------------------------------------

#define D128 128
#define XP 136                    // padded fp16 row length (272B, %16==0)

typedef _Float16 f16x2 __attribute__((ext_vector_type(2)));
typedef _Float16 f16x8 __attribute__((ext_vector_type(8)));
typedef float f32x4 __attribute__((ext_vector_type(4)));

union U4 { uint4 u; f16x2 f2[4]; __half2 hh[4]; };

__device__ __forceinline__ void threefry2x32(unsigned x0, unsigned x1,
                                             unsigned& o0, unsigned& o1) {
  const unsigned k0 = 0u, k1 = 42u;
  const unsigned k2 = 0x1BD11BDAu ^ k0 ^ k1;
  x0 += k0; x1 += k1;
#define TF_ROT(r) { x0 += x1; x1 = (x1 << (r)) | (x1 >> (32 - (r))); x1 ^= x0; }
  TF_ROT(13) TF_ROT(15) TF_ROT(26) TF_ROT(6)
  x0 += k1; x1 += k2 + 1u;
  TF_ROT(17) TF_ROT(29) TF_ROT(16) TF_ROT(24)
  x0 += k2; x1 += k0 + 2u;
  TF_ROT(13) TF_ROT(15) TF_ROT(26) TF_ROT(6)
  x0 += k0; x1 += k1 + 3u;
  TF_ROT(17) TF_ROT(29) TF_ROT(16) TF_ROT(24)
  x0 += k1; x1 += k2 + 4u;
  TF_ROT(13) TF_ROT(15) TF_ROT(26) TF_ROT(6)
  x0 += k2; x1 += k0 + 5u;
#undef TF_ROT
  o0 = x0; o1 = x1;
}

// blocks [0,24): W fp32->fp16 (3 x 2048 chunks of 8). blocks [24,...): counts.
__global__ __launch_bounds__(256) void cvt_count_kernel(
    const float* __restrict__ Wq, const float* __restrict__ Wk,
    const float* __restrict__ Wa, __half* __restrict__ wqh,
    __half* __restrict__ wkh, __half* __restrict__ wah,
    const int* __restrict__ src, int* __restrict__ counts, int E) {
  int b = blockIdx.x;
  if (b < 24) {
    int i = b * 256 + threadIdx.x;
    int w = i >> 11, r = i & 2047;
    if (w >= 3) return;
    size_t off = (size_t)r * 8;
    const float* s = (w == 0) ? Wq : (w == 1) ? Wk : Wa;
    __half* d = (w == 0) ? wqh : (w == 1) ? wkh : wah;
    float4 a = *reinterpret_cast<const float4*>(s + off);
    float4 c = *reinterpret_cast<const float4*>(s + off + 4);
    union { __half2 h2[4]; uint4 u; } pk;
    pk.h2[0] = __floats2half2_rn(a.x, a.y);
    pk.h2[1] = __floats2half2_rn(a.z, a.w);
    pk.h2[2] = __floats2half2_rn(c.x, c.y);
    pk.h2[3] = __floats2half2_rn(c.z, c.w);
    *reinterpret_cast<uint4*>(d + off) = pk.u;
  } else {
    int e = (b - 24) * 256 + threadIdx.x;
    if (e < E) atomicAdd(&counts[src[e]], 1);
  }
}

// One kernel, three GEMM passes from a single X staging.
__global__ __launch_bounds__(256) void gemm3_kernel(
    const float* __restrict__ X, const __half* __restrict__ wqh_g,
    const __half* __restrict__ wkh_g, const __half* __restrict__ wah_g,
    const float* __restrict__ lsq, const float* __restrict__ lsk,
    __half* __restrict__ qout, __half* __restrict__ kout,
    __half* __restrict__ aout, int N) {
  __shared__ __align__(16) _Float16 xs[64 * XP];
  __shared__ __align__(16) _Float16 wh[128 * XP];

  const int t = threadIdx.x;
  const int row0 = blockIdx.x * 64;

  // stage X fp32 -> fp16 LDS
#pragma unroll
  for (int i = 0; i < 8; ++i) {
    int f = t + 256 * i, r = f >> 5, c4 = f & 31;
    float4 v = make_float4(0.f, 0.f, 0.f, 0.f);
    if (row0 + r < N)
      v = *reinterpret_cast<const float4*>(X + (size_t)(row0 + r) * D128 + c4 * 4);
    union { _Float16 h[4]; uint2 u; } p;
    p.h[0] = (_Float16)v.x; p.h[1] = (_Float16)v.y;
    p.h[2] = (_Float16)v.z; p.h[3] = (_Float16)v.w;
    *reinterpret_cast<uint2*>(&xs[r * XP + c4 * 4]) = p.u;
  }

  const int w = t >> 6, lane = t & 63;
  const int lc = lane & 15;
  const int arow = 16 * w + lc;
  const int koff = (lane >> 4) * 8;

  for (int p = 0; p < 3; ++p) {
    __syncthreads();   // xs writes done (p=0); prev MFMA done reading wh (p>0)
    const __half* Wg = (p == 0) ? wqh_g : (p == 1) ? wkh_g : wah_g;
#pragma unroll
    for (int i = 0; i < 8; ++i) {
      int f = t + 256 * i, wr = f >> 4, c8 = f & 15;
      *reinterpret_cast<uint4*>(&wh[wr * XP + c8 * 8]) =
          *reinterpret_cast<const uint4*>(Wg + (size_t)wr * D128 + c8 * 8);
    }

    if (p == 2) {
      // logmap0 in place on xs (K-pass MFMA reads finished at top sync)
#pragma unroll
      for (int rr = 0; rr < 2; ++rr) {
        int r = (t >> 3) + 32 * rr, tr = t & 7;
        U4 c0, c1;
        c0.u = *reinterpret_cast<uint4*>(&xs[r * XP + tr * 16]);
        c1.u = *reinterpret_cast<uint4*>(&xs[r * XP + tr * 16 + 8]);
        float v[16];
        float ss = 0.f;
#pragma unroll
        for (int j = 0; j < 4; ++j) {
          float2 f = __half22float2(c0.hh[j]);
          v[2 * j] = f.x; v[2 * j + 1] = f.y; ss += f.x * f.x + f.y * f.y;
        }
#pragma unroll
        for (int j = 0; j < 4; ++j) {
          float2 f = __half22float2(c1.hh[j]);
          v[8 + 2 * j] = f.x; v[9 + 2 * j] = f.y; ss += f.x * f.x + f.y * f.y;
        }
        if (tr == 0) ss -= v[0] * v[0];
#pragma unroll
        for (int msk = 1; msk < 8; msk <<= 1) ss += __shfl_xor(ss, msk);
        float x0v = __shfl(v[0], (t & 63) & ~7);
        float dd = acoshf(fmaxf(x0v, 1.f + 1e-6f));
        float sc = dd / fmaxf(sqrtf(ss), 1e-8f);
#pragma unroll
        for (int j = 0; j < 16; ++j) v[j] *= sc;
        if (tr == 0) v[0] = 0.f;
        union { __half2 h2[4]; uint4 u; } pk;
#pragma unroll
        for (int j = 0; j < 4; ++j) pk.h2[j] = __floats2half2_rn(v[2 * j], v[2 * j + 1]);
        *reinterpret_cast<uint4*>(&xs[r * XP + tr * 16]) = pk.u;
#pragma unroll
        for (int j = 0; j < 4; ++j) pk.h2[j] = __floats2half2_rn(v[8 + 2 * j], v[9 + 2 * j]);
        *reinterpret_cast<uint4*>(&xs[r * XP + tr * 16 + 8]) = pk.u;
      }
    }
    __syncthreads();

    f32x4 acc[8];
#pragma unroll
    for (int i = 0; i < 8; ++i) acc[i] = (f32x4){0.f, 0.f, 0.f, 0.f};
#pragma unroll
    for (int kk = 0; kk < 4; ++kk) {
      f16x8 a = *reinterpret_cast<f16x8*>(&xs[arow * XP + kk * 32 + koff]);
#pragma unroll
      for (int tt = 0; tt < 8; ++tt) {
        f16x8 b = *reinterpret_cast<f16x8*>(&wh[(tt * 16 + lc) * XP + kk * 32 + koff]);
        acc[tt] = __builtin_amdgcn_mfma_f32_16x16x32_f16(a, b, acc[tt], 0, 0, 0);
      }
    }

    if (p < 2) {
      // lorentz tail; q narrow negated
      float scale = expf(p ? lsk[0] : lsq[0]);
      __half* outp = p ? kout : qout;
      float sgn = p ? 1.f : -1.f;
#pragma unroll
      for (int j = 0; j < 4; ++j) {
        int gr = row0 + 16 * w + ((lane >> 4) << 2) + j;
        float ss = 0.f;
#pragma unroll
        for (int tt = 0; tt < 8; ++tt) {
          float v = acc[tt][j];
          if (tt == 0 && lc == 0) v = 0.f;
          ss += v * v;
        }
#pragma unroll
        for (int msk = 1; msk < 16; msk <<= 1) ss += __shfl_xor(ss, msk);
        float y0 = __shfl(acc[0][j], lane & ~15);
        float tm = scale / (1.f + expf(-y0)) + 1.1f;
        float qs = sqrtf((tm * tm - 1.f) / fmaxf(ss, 1e-8f)) * sgn;
        if (gr < N) {
#pragma unroll
          for (int tt = 0; tt < 8; ++tt) {
            float val = acc[tt][j] * qs;
            if (tt == 0 && lc == 0) val = tm;
            outp[(size_t)gr * D128 + tt * 16 + lc] = __float2half(val);
          }
        }
      }
    } else {
      // row softmax -> ass
#pragma unroll
      for (int j = 0; j < 4; ++j) {
        int gr = row0 + 16 * w + ((lane >> 4) << 2) + j;
        float mx = acc[0][j];
#pragma unroll
        for (int tt = 1; tt < 8; ++tt) mx = fmaxf(mx, acc[tt][j]);
#pragma unroll
        for (int msk = 1; msk < 16; msk <<= 1) mx = fmaxf(mx, __shfl_xor(mx, msk));
        float e[8], sm = 0.f;
#pragma unroll
        for (int tt = 0; tt < 8; ++tt) { e[tt] = expf(acc[tt][j] - mx); sm += e[tt]; }
#pragma unroll
        for (int msk = 1; msk < 16; msk <<= 1) sm += __shfl_xor(sm, msk);
        float inv = 1.f / sm;
        if (gr < N) {
#pragma unroll
          for (int tt = 0; tt < 8; ++tt)
            aout[(size_t)gr * D128 + tt * 16 + lc] = __float2half(e[tt] * inv);
        }
      }
    }
  }
}

// --- 3-kernel exclusive scan of counts -> start, cursor ---
__global__ __launch_bounds__(256) void scan1_kernel(const int* __restrict__ counts,
                                                    int* __restrict__ incl,
                                                    int* __restrict__ partials, int N) {
  int i = blockIdx.x * 256 + threadIdx.x;
  int c = (i < N) ? counts[i] : 0;
  int lane = threadIdx.x & 63, w = threadIdx.x >> 6;
  int v = c;
#pragma unroll
  for (int d = 1; d < 64; d <<= 1) {
    int tv = __shfl_up(v, d);
    if (lane >= d) v += tv;
  }
  __shared__ int wsum[4];
  if (lane == 63) wsum[w] = v;
  __syncthreads();
  int add = 0;
  for (int j = 0; j < w; ++j) add += wsum[j];
  v += add;
  if (i < N) incl[i] = v;
  if (threadIdx.x == 255) partials[blockIdx.x] = v;
}

__global__ __launch_bounds__(256) void scan2_kernel(int* __restrict__ partials, int nparts) {
  int t = threadIdx.x;
  int p = (t < nparts) ? partials[t] : 0;
  int lane = t & 63, w = t >> 6;
  int v = p;
#pragma unroll
  for (int d = 1; d < 64; d <<= 1) {
    int tv = __shfl_up(v, d);
    if (lane >= d) v += tv;
  }
  __shared__ int wsum[4];
  if (lane == 63) wsum[w] = v;
  __syncthreads();
  int add = 0;
  for (int j = 0; j < w; ++j) add += wsum[j];
  v += add;
  if (t < nparts) partials[t] = v - p;
}

__global__ __launch_bounds__(256) void scan3_kernel(const int* __restrict__ counts,
                                                    int* __restrict__ incl_to_start,
                                                    int* __restrict__ cursor,
                                                    const int* __restrict__ partials, int N) {
  int i = blockIdx.x * 256 + threadIdx.x;
  if (i < N) {
    int s = incl_to_start[i] - counts[i] + partials[blockIdx.x];
    incl_to_start[i] = s;
    cursor[i] = s;
  }
}

// scatter dst into CSR (segment-sorted) order
__global__ __launch_bounds__(256) void csr_fill_kernel(
    const int* __restrict__ src, const int* __restrict__ dst,
    int* __restrict__ cursor, int* __restrict__ dst_s, int E) {
  int e = blockIdx.x * 256 + threadIdx.x;
  if (e < E) {
    int pos = atomicAdd(&cursor[src[e]], 1);
    dst_s[pos] = dst[e];
  }
}

// One 16-lane group per node; prefetch-2 pipeline; closed-form softmax weight.
__global__ __launch_bounds__(256) void node_fused_kernel(
    const __half* __restrict__ qh, const __half* __restrict__ kh,
    const __half* __restrict__ ass, const int* __restrict__ start,
    const int* __restrict__ counts, const int* __restrict__ dst_s,
    float* __restrict__ out, int N) {
  int g = threadIdx.x >> 4;
  int lq = threadIdx.x & 15;
  int n = blockIdx.x * 16 + g;
  if (n >= N) return;
  int st = start[n], deg = counts[n];
  int c8 = lq * 8;

  U4 qv;
  qv.u = *reinterpret_cast<const uint4*>(qh + (size_t)n * D128 + c8);

  float lsum = 0.f;
  float acc[8];
#pragma unroll
  for (int j = 0; j < 8; ++j) acc[j] = 0.f;

  if (deg > 0) {
    int d0 = dst_s[st];
    int d1 = (deg > 1) ? dst_s[st + 1] : d0;
    U4 kv0, av0, kv1, av1;
    kv0.u = *reinterpret_cast<const uint4*>(kh + (size_t)d0 * D128 + c8);
    av0.u = *reinterpret_cast<const uint4*>(ass + (size_t)d0 * D128 + c8);
    kv1.u = *reinterpret_cast<const uint4*>(kh + (size_t)d1 * D128 + c8);
    av1.u = *reinterpret_cast<const uint4*>(ass + (size_t)d1 * D128 + c8);

    for (int i = 0; i < deg; ++i) {
      // prefetch edge i+2
      int p2 = st + i + 2;
      int d2 = dst_s[(p2 < st + deg) ? p2 : st];
      U4 kv2, av2;
      kv2.u = *reinterpret_cast<const uint4*>(kh + (size_t)d2 * D128 + c8);
      av2.u = *reinterpret_cast<const uint4*>(ass + (size_t)d2 * D128 + c8);

      // dot via two independent fdot2 chains
      float pa = __builtin_amdgcn_fdot2(qv.f2[0], kv0.f2[0],
                 __builtin_amdgcn_fdot2(qv.f2[1], kv0.f2[1], 0.f, false), false);
      float pb = __builtin_amdgcn_fdot2(qv.f2[2], kv0.f2[2],
                 __builtin_amdgcn_fdot2(qv.f2[3], kv0.f2[3], 0.f, false), false);
      float part = pa + pb;
#pragma unroll
      for (int msk = 1; msk < 16; msk <<= 1) part += __shfl_xor(part, msk);

      // w = exp(-acosh(x)) = 1/(x + sqrt(x^2-1)), x clipped to 1+1e-6
      float x = fmaxf(part, 1.f + 1e-6f);
      float tt = x + sqrtf(__builtin_fmaf(x, x, -1.f));
      float w = __builtin_amdgcn_rcpf(tt);

      lsum += w;
      float2 v0 = __half22float2(av0.hh[0]);
      float2 v1 = __half22float2(av0.hh[1]);
      float2 v2 = __half22float2(av0.hh[2]);
      float2 v3 = __half22float2(av0.hh[3]);
      acc[0] += w * v0.x;  acc[1] += w * v0.y;
      acc[2] += w * v1.x;  acc[3] += w * v1.y;
      acc[4] += w * v2.x;  acc[5] += w * v2.y;
      acc[6] += w * v3.x;  acc[7] += w * v3.y;

      kv0 = kv1; av0 = av1;
      kv1 = kv2; av1 = av2;
    }
  }

  float inv = (deg > 0) ? 1.f / fmaxf(lsum, 1e-8f) : 0.f;

  float vg[8];
#pragma unroll
  for (int j = 0; j < 8; ++j) {
    unsigned o0, o1;
    threefry2x32(0u, (unsigned)(n * D128 + c8 + j), o0, o1);
    unsigned bits = o0 ^ o1;
    float f = __uint_as_float((bits >> 9) | 0x3f800000u) - 1.0f;
    float u = fmaxf(1e-10f, f * (1.0f - 1e-10f) + 1e-10f);
    float gmb = -logf(-logf(u));
    vg[j] = (logf(acc[j] * inv + 1e-6f) + gmb) / 0.2f;
  }
  float mm = vg[0];
#pragma unroll
  for (int j = 1; j < 8; ++j) mm = fmaxf(mm, vg[j]);
#pragma unroll
  for (int msk = 1; msk < 16; msk <<= 1) mm = fmaxf(mm, __shfl_xor(mm, msk));
  float sm = 0.f;
#pragma unroll
  for (int j = 0; j < 8; ++j) { vg[j] = expf(vg[j] - mm); sm += vg[j]; }
#pragma unroll
  for (int msk = 1; msk < 16; msk <<= 1) sm += __shfl_xor(sm, msk);
  float invs = 1.f / sm;
  *reinterpret_cast<float4*>(out + (size_t)n * D128 + c8) =
      make_float4(vg[0] * invs, vg[1] * invs, vg[2] * invs, vg[3] * invs);
  *reinterpret_cast<float4*>(out + (size_t)n * D128 + c8 + 4) =
      make_float4(vg[4] * invs, vg[5] * invs, vg[6] * invs, vg[7] * invs);
}

extern "C" void kernel_launch(void* const* d_in, const int* in_sizes, int n_in,
                              void* d_out, int out_size, void* d_ws, size_t ws_size,
                              hipStream_t stream) {
  const float* x   = (const float*)d_in[0];
  const int*   src = (const int*)d_in[1];
  const int*   dst = (const int*)d_in[2];
  // d_in[3] = edge_value (unused by reference)
  const float* Wq  = (const float*)d_in[4];
  const float* Wk  = (const float*)d_in[5];
  const float* Wa  = (const float*)d_in[6];
  const float* lsq = (const float*)d_in[7];
  const float* lsk = (const float*)d_in[8];
  const int N = in_sizes[0] / D128;
  const int E = in_sizes[1];
  float* out = (float*)d_out;

  __half* qh   = (__half*)d_ws;
  __half* kh   = qh + (size_t)N * D128;
  __half* ah   = kh + (size_t)N * D128;
  __half* wqh  = ah + (size_t)N * D128;
  __half* wkh  = wqh + 16384;
  __half* wah  = wkh + 16384;
  int* counts  = (int*)(wah + 16384);
  int* startv  = counts + N;
  int* cursor  = startv + N;
  int* partials= cursor + N;
  int* dst_s   = partials + 256;

  hipMemsetAsync(counts, 0, (size_t)N * sizeof(int), stream);

  const int eb = (E + 255) / 256;
  cvt_count_kernel<<<24 + eb, 256, 0, stream>>>(Wq, Wk, Wa, wqh, wkh, wah,
                                                src, counts, E);

  const int gemm_blocks = (N + 63) / 64;
  gemm3_kernel<<<gemm_blocks, 256, 0, stream>>>(x, wqh, wkh, wah, lsq, lsk,
                                                qh, kh, ah, N);

  const int nb = (N + 255) / 256;
  scan1_kernel<<<nb, 256, 0, stream>>>(counts, startv, partials, N);
  scan2_kernel<<<1, 256, 0, stream>>>(partials, nb);
  scan3_kernel<<<nb, 256, 0, stream>>>(counts, startv, cursor, partials, N);
  csr_fill_kernel<<<eb, 256, 0, stream>>>(src, dst, cursor, dst_s, E);

  node_fused_kernel<<<(N + 15) / 16, 256, 0, stream>>>(qh, kh, ah, startv,
                                                       counts, dst_s, out, N);
}